// Round 12
// baseline (676.637 us; speedup 1.0000x reference)
//
#include <hip/hip_runtime.h>
#include <hip/hip_bf16.h>
#include <stdint.h>

#define TT 6
#define PP 8
#define HH 8
#define DD 512
#define FF 1024
#define DH 64
#define NB 4
#define NN 4096
#define LL 12
#define NCH 16
#define CHK 256
#define NXB 128   // k_xcv n-blocks (32 rows each)

typedef __attribute__((ext_vector_type(8))) short short8v;
typedef __attribute__((ext_vector_type(4))) float f32x4;
typedef __attribute__((ext_vector_type(4))) unsigned short u16x4;
typedef __attribute__((ext_vector_type(8))) unsigned short u16x8;
typedef unsigned short u16;

__device__ __forceinline__ float bf2f(u16 u){
  union { unsigned int i; float f; } x; x.i = ((unsigned int)u) << 16; return x.f;
}
__device__ __forceinline__ u16 f2bf(float f){
  union { float f; unsigned int i; } x; x.f = f;
  unsigned int r = x.i + 0x7fffu + ((x.i >> 16) & 1u);
  return (u16)(r >> 16);
}
__device__ __forceinline__ float wave_sum(float x){
  #pragma unroll
  for (int o = 32; o > 0; o >>= 1) x += __shfl_xor(x, o);
  return x;
}
__device__ __forceinline__ float ldf(const void* p, size_t i, int f32){
  float v;
  if (f32) v = ((const float*)p)[i];
  else     v = bf2f(((const u16*)p)[i]);
  return v;
}
// Vectorized block GEMV: y[d] = sum_k xs[k]*W[wbase + k*DD + d], d = tid in [0,512).
__device__ __forceinline__ float gemv_vec(const float* __restrict__ xs,
    const void* __restrict__ W, size_t wbase, int ktot, int wf32,
    float* __restrict__ red, int tid){
  int g = tid & 63, sl = tid >> 6;
  int kpw = ktot >> 3;
  float a[8] = {0,0,0,0,0,0,0,0};
  if (wf32){
    const float* Wp = (const float*)W + wbase + (size_t)(sl*kpw)*DD + g*8;
    #pragma unroll 4
    for (int i = 0; i < kpw; ++i){
      float xv = xs[sl*kpw + i];
      f32x4 lo = *(const f32x4*)(Wp + (size_t)i*DD);
      f32x4 hi = *(const f32x4*)(Wp + (size_t)i*DD + 4);
      a[0]+=xv*lo.x; a[1]+=xv*lo.y; a[2]+=xv*lo.z; a[3]+=xv*lo.w;
      a[4]+=xv*hi.x; a[5]+=xv*hi.y; a[6]+=xv*hi.z; a[7]+=xv*hi.w;
    }
  } else {
    const u16* Wp = (const u16*)W + wbase + (size_t)(sl*kpw)*DD + g*8;
    #pragma unroll 4
    for (int i = 0; i < kpw; ++i){
      float xv = xs[sl*kpw + i];
      u16x8 w8 = *(const u16x8*)(Wp + (size_t)i*DD);
      #pragma unroll
      for (int j = 0; j < 8; ++j) a[j] += xv * bf2f(w8[j]);
    }
  }
  #pragma unroll
  for (int j = 0; j < 8; ++j) red[sl*512 + g*8 + j] = a[j];
  __syncthreads();
  float y = 0;
  #pragma unroll
  for (int s2 = 0; s2 < 8; ++s2) y += red[s2*512 + tid];
  return y;
}
// async global->LDS, 16B per lane. Global src IS per-lane (gather/swizzle OK);
// LDS dest must be wave-uniform base + lane*16 (linear).
__device__ __forceinline__ void glds16(const void* g, void* l){
#if __has_builtin(__builtin_amdgcn_global_load_lds)
  __builtin_amdgcn_global_load_lds(
      (const __attribute__((address_space(1))) void*)g,
      (__attribute__((address_space(3))) void*)l, 16, 0, 0);
#else
  *(u16x8*)l = *(const u16x8*)g;
#endif
}
// MFMA tail helpers (b-split tailm): M=16 (8 real rows + 8 zero-pad) x
// N=64-per-wave GEMM, A in LDS [16][520] bf16, B from transposed Wt[d][k].
__device__ __forceinline__ void tail_gemm8(f32x4 acc[4], const u16* __restrict__ Bp,
    const u16* As, int l15, int q4, int n0w){
  #pragma unroll
  for (int ni = 0; ni < 4; ++ni){ f32x4 z = {0,0,0,0}; acc[ni] = z; }
  #pragma unroll 2
  for (int k0 = 0; k0 < 512; k0 += 32){
    short8v bf[4], af;
    #pragma unroll
    for (int ni = 0; ni < 4; ++ni)
      bf[ni] = *(const short8v*)(Bp + (size_t)(n0w + ni*16 + l15)*DD + k0 + q4*8);
    af = *(const short8v*)(As + l15*520 + k0 + q4*8);
    #pragma unroll
    for (int ni = 0; ni < 4; ++ni)
      acc[ni] = __builtin_amdgcn_mfma_f32_16x16x32_bf16(af, bf[ni], acc[ni], 0, 0, 0);
  }
}
__device__ __forceinline__ void row_ln8(const f32x4 acc[4],
    float* red1, float* red2, int w, int l15, int q4,
    float mv[4], float rv[4]){
  float s1[4], s2[4];
  #pragma unroll
  for (int r = 0; r < 4; ++r){
    float a0=acc[0][r], a1=acc[1][r], a2=acc[2][r], a3=acc[3][r];
    s1[r] = (a0+a1)+(a2+a3);
    s2[r] = (a0*a0+a1*a1)+(a2*a2+a3*a3);
  }
  #pragma unroll
  for (int o = 1; o < 16; o <<= 1)
    #pragma unroll
    for (int r = 0; r < 4; ++r){
      s1[r] += __shfl_xor(s1[r], o);
      s2[r] += __shfl_xor(s2[r], o);
    }
  if (l15 == 0){
    #pragma unroll
    for (int r = 0; r < 4; ++r){
      int row = q4*4 + r;
      red1[row*8 + w] = s1[r];
      red2[row*8 + w] = s2[r];
    }
  }
  __syncthreads();
  #pragma unroll
  for (int r = 0; r < 4; ++r){
    int row = q4*4 + r;
    float S1 = 0, S2 = 0;
    #pragma unroll
    for (int j = 0; j < 8; ++j){ S1 += red1[row*8+j]; S2 += red2[row*8+j]; }
    float m = S1 * (1.f/DD);
    float var = S2 * (1.f/DD) - m*m;
    mv[r] = m;
    rv[r] = rsqrtf(var + 1e-5f);
  }
  __syncthreads();
}

// flag=1 -> inputs are float32 ; flag=0 -> inputs are bf16
__global__ void k_detect(const void* __restrict__ X, int* __restrict__ flag){
  int tid = threadIdx.x;
  const u16* u = (const u16*)X;
  int bad = 0;
  for (int i = tid; i < 8192; i += 256){
    int ex = (u[i] >> 7) & 0xFF;
    if (ex >= 0x90) bad = 1;
  }
  __shared__ int s;
  if (tid == 0) s = 0;
  __syncthreads();
  if (bad) s = 1;
  __syncthreads();
  if (tid == 0) *flag = s;
}

// fused dual f32->bf16 (or bf16 copy) converter: array0 quads [0,n0q),
// array1 quads [n0q, ...). One dispatch for pmW + Wq.
__global__ void k_cvt2(const void* __restrict__ s0, u16* __restrict__ d0, int n0q,
                       const void* __restrict__ s1, u16* __restrict__ d1,
                       const int* __restrict__ flagp){
  int f32 = *flagp;
  size_t q = (size_t)blockIdx.x*256 + threadIdx.x;
  const void* s; u16* d; size_t i;
  if (q < (size_t)n0q){ s = s0; d = d0; i = q*4; }
  else                { s = s1; d = d1; i = (q - n0q)*4; }
  if (f32){
    f32x4 v = *(const f32x4*)((const float*)s + i);
    u16x4 o; o.x=f2bf(v.x); o.y=f2bf(v.y); o.z=f2bf(v.z); o.w=f2bf(v.w);
    *(u16x4*)(d+i) = o;
  } else {
    *(u16x4*)(d+i) = *(const u16x4*)((const u16*)s + i);
  }
}

// FUSED X pass: X -> bf16 copy + per-type column PARTIALS (no f32 atomics).
// Partials go to Pcol/Ptot (carved from Kb; kvgemm writes Kb only after k_mu
// consumed them -> stream-safe). cnt/bmsum keep tiny integer atomics (exact).
__global__ void k_xcv(const void* __restrict__ X, u16* __restrict__ Xb,
                      const int* __restrict__ bm, const int* __restrict__ ntype,
                      float* __restrict__ Pcol, float* __restrict__ Ptot,
                      float* __restrict__ cnt, float* __restrict__ bmsum,
                      const int* __restrict__ flagp){
  int f32 = *flagp;
  int b = blockIdx.y, blk = blockIdx.x;
  int n0 = blk * 32;
  int tid = threadIdx.x;
  int f0 = tid * 4;
  __shared__ int sflag[32];
  __shared__ float scnt[TT+1];
  if (tid < 32) sflag[tid] = 0;
  if (tid < TT+1) scnt[tid] = 0.f;
  __syncthreads();
  float acc[TT][4] = {};
  float tot[4] = {0,0,0,0};
  for (int i = 0; i < 32; ++i){
    int n = n0 + i;
    size_t idx = (size_t)(b*NN+n)*FF + f0;
    u16x4 xb;
    bool a;
    if (f32){
      f32x4 v = *(const f32x4*)((const float*)X + idx);
      xb.x=f2bf(v.x); xb.y=f2bf(v.y); xb.z=f2bf(v.z); xb.w=f2bf(v.w);
      a = (v.x!=0.f)||(v.y!=0.f)||(v.z!=0.f)||(v.w!=0.f);
    } else {
      xb = *(const u16x4*)((const u16*)X + idx);
      a = (bf2f(xb.x)!=0.f)||(bf2f(xb.y)!=0.f)||(bf2f(xb.z)!=0.f)||(bf2f(xb.w)!=0.f);
    }
    *(u16x4*)(Xb+idx) = xb;
    if (a) sflag[i] = 1;
    float vbm = (bm[b*NN+n] != 0) ? 1.f : 0.f;
    int ty = ntype[b*NN+n];
    #pragma unroll
    for (int j = 0; j < 4; ++j){
      float xv = bf2f(xb[j]);
      tot[j] += xv;
      float xvv = xv * vbm;
      #pragma unroll
      for (int t = 0; t < TT; ++t) acc[t][j] += (ty==t) ? xvv : 0.f;
    }
  }
  __syncthreads();
  if (tid < 32){
    int n = n0 + tid;
    if (bm[b*NN+n] != 0){
      if (sflag[tid]) atomicAdd(&scnt[ntype[b*NN+n]], 1.f);
      atomicAdd(&scnt[TT], 1.f);
    }
  }
  size_t pbase = (size_t)blk*NB + b;
  #pragma unroll
  for (int t = 0; t < TT; ++t){
    f32x4 v = {acc[t][0], acc[t][1], acc[t][2], acc[t][3]};
    *(f32x4*)&Pcol[(pbase*TT + t)*FF + f0] = v;
  }
  {
    f32x4 v = {tot[0], tot[1], tot[2], tot[3]};
    *(f32x4*)&Ptot[pbase*FF + f0] = v;
  }
  __syncthreads();
  if (tid < TT) atomicAdd(&cnt[b*TT + tid], scnt[tid]);
  if (tid == TT) atomicAdd(&bmsum[b], scnt[TT]);
}

// fold the NXB partials -> colsums/coltotal (r12: was inside k_mu on only 24
// blocks, serial 128-deep per thread -> latency-bound; 96 blocks here).
// Same ascending blk add order as before -> bitwise identical.
__global__ void k_fold(const float* __restrict__ Pcol, const float* __restrict__ Ptot,
                       float* __restrict__ colsums, float* __restrict__ coltotal){
  int fb = blockIdx.x;            // 0..3
  int bt = blockIdx.y;            // 0..NB*TT-1
  int b = bt / TT, t = bt % TT;
  int f = fb*256 + threadIdx.x;
  float S = 0.f;
  #pragma unroll 4
  for (int blk = 0; blk < NXB; ++blk)
    S += Pcol[(((size_t)blk*NB + b)*TT + t)*FF + f];
  colsums[(size_t)bt*FF + f] = S;
  if (t == 0){
    float T = 0.f;
    #pragma unroll 4
    for (int blk = 0; blk < NXB; ++blk)
      T += Ptot[((size_t)blk*NB + b)*FF + f];
    coltotal[b*FF + f] = T;
  }
}

// per-batch stable compaction of valid (bm!=0) key indices
__global__ void k_compact(const int* __restrict__ bm, int* __restrict__ nidx,
                          int* __restrict__ cntc){
  int b = blockIdx.x, tid = threadIdx.x;   // 256 threads, 16 entries each
  __shared__ int csum[256];
  __shared__ int pref[257];
  int base = b*NN + tid*16;
  int f[16]; int loc = 0;
  #pragma unroll
  for (int i = 0; i < 16; ++i){ f[i] = (bm[base+i] != 0); loc += f[i]; }
  csum[tid] = loc;
  __syncthreads();
  if (tid == 0){
    pref[0] = 0;
    for (int j = 0; j < 256; ++j) pref[j+1] = pref[j] + csum[j];
  }
  __syncthreads();
  int off = b*NN + pref[tid];
  #pragma unroll
  for (int i = 0; i < 16; ++i){ if (f[i]) nidx[off++] = tid*16 + i; }
  if (tid == 0) cntc[b] = pref[256];
}

// Wq/Wo/Wm1/Wm2 -> TRANSPOSED bf16 Wt[fam][c][d][k]
__global__ void k_wbfT(const void* __restrict__ Wq, const void* __restrict__ Wo,
                       const void* __restrict__ Wm1, const void* __restrict__ Wm2,
                       u16* __restrict__ Wt, const int* __restrict__ flagp){
  int f32 = *flagp;
  int z = blockIdx.z;                 // fam*LL + c
  int fam = z / LL;
  const void* src = (fam==0) ? Wq : (fam==1) ? Wo : (fam==2) ? Wm1 : Wm2;
  size_t sbase = (size_t)(z % LL) * DD * DD;
  __shared__ u16 tile[32][33];
  int d0 = blockIdx.x*32, k0 = blockIdx.y*32;
  int tx = threadIdx.x, ty = threadIdx.y;   // 32x8
  #pragma unroll
  for (int i = 0; i < 4; ++i){
    size_t idx = sbase + (size_t)(k0 + ty + i*8)*DD + d0 + tx;
    u16 v;
    if (f32) v = f2bf(((const float*)src)[idx]);
    else     v = ((const u16*)src)[idx];
    tile[ty + i*8][tx] = v;            // tile[k][d]
  }
  __syncthreads();
  #pragma unroll
  for (int i = 0; i < 4; ++i)
    Wt[((size_t)z*DD + d0 + ty + i*8)*DD + k0 + tx] = tile[tx][ty + i*8];
}

// FUSED proto_mu + mu (folded inputs): writes the proto_mu region of d_out,
// then the pmW GEMV + LN + gelu + expand.
__global__ void __launch_bounds__(512) k_mu(const float* __restrict__ colsums,
   const float* __restrict__ coltotal, const float* __restrict__ cnt,
   const float* __restrict__ bmsum,
   const void* __restrict__ pmWx, const void* __restrict__ pmb,
   const void* __restrict__ pmg, const void* __restrict__ pmbn,
   const void* __restrict__ lsig, const void* __restrict__ rmul,
   float* __restrict__ qstate, void* __restrict__ dout, int wmode,
   const int* __restrict__ flagp){
  int f32 = *flagp;
  int wf32 = wmode ? f32 : 0;
  const size_t OFFP = (size_t)NB*TT*PP*DD;
  int bt = blockIdx.x; int b = bt/TT, t = bt%TT;
  int d = threadIdx.x;
  __shared__ float xs[FF];
  __shared__ float red[4096];
  __shared__ float r1[8], r2[8];
  float cv = cnt[bt];
  float inv = 1.f / fmaxf(cv, 1.f);
  float fbinv = 1.f / bmsum[b];
  #pragma unroll
  for (int h = 0; h < 2; ++h){
    int f = d + h*512;
    float pm = (cv > 0.f) ? colsums[(size_t)bt*FF + f] * inv
                          : coltotal[b*FF + f] * fbinv;
    xs[f] = pm;
    if (f32) ((float*)dout)[OFFP + (size_t)bt*FF + f] = pm;
    else     ((u16*)dout)[OFFP + (size_t)bt*FF + f] = f2bf(pm);
  }
  __syncthreads();
  float acc = ldf(pmb, d, f32) + gemv_vec(xs, pmWx, 0, FF, wf32, red, d);
  int lane = d & 63, wid = d >> 6;
  float s1 = wave_sum(acc), s2 = wave_sum(acc*acc);
  if (lane==0){ r1[wid]=s1; r2[wid]=s2; }
  __syncthreads();
  float m=0, qq=0;
  #pragma unroll
  for (int i=0;i<8;++i){ m+=r1[i]; qq+=r2[i]; }
  m *= (1.f/DD); float var = qq*(1.f/DD) - m*m;
  float y = (acc - m) * rsqrtf(var + 1e-5f) * ldf(pmg, d, f32) + ldf(pmbn, d, f32);
  float mu = 0.5f * y * (1.f + erff(y * 0.70710678118654752f));
  #pragma unroll
  for (int p = 0; p < PP; ++p){
    float rv = ldf(rmul, (size_t)(t*PP+p)*DD + d, f32);
    float ls = ldf(lsig, (size_t)t*DD + d, f32);
    qstate[(((size_t)(b*TT+t))*PP + p)*DD + d] = mu + expf(ls) * rv;
  }
}

// batched transpose: z = ti*2 + kv ; layer c = 2*(tlo+ti)+s
__global__ void k_transpose(const void* __restrict__ Wk, const void* __restrict__ Wv,
                            u16* __restrict__ TK, u16* __restrict__ TV,
                            int tlo, int s, const int* __restrict__ flagp){
  int f32 = *flagp;
  int ti = blockIdx.z >> 1, kv = blockIdx.z & 1;
  int c = 2*(tlo+ti)+s;
  size_t eoff = (size_t)c*FF*DD;
  const void* W = kv ? Wv : Wk;
  u16* T = (kv ? TV : TK) + (size_t)ti*FF*DD;
  __shared__ u16 tile[32][33];
  int n0 = blockIdx.x * 32, k0 = blockIdx.y * 32;
  int tx = threadIdx.x, ty = threadIdx.y;
  #pragma unroll
  for (int i = 0; i < 4; ++i){
    size_t idx = eoff + (size_t)(k0 + ty + i*8)*DD + n0 + tx;
    u16 v;
    if (f32) v = f2bf(((const float*)W)[idx]);
    else     v = ((const u16*)W)[idx];
    tile[ty + i*8][tx] = v;
  }
  __syncthreads();
  #pragma unroll
  for (int i = 0; i < 4; ++i)
    T[(size_t)(n0 + ty + i*8)*FF + k0 + tx] = tile[tx][ty + i*8];
}

// ---- K/V GEMM: BM=256 x BN=128, BK=32, 512 thr / 8 waves, 3-buffer LDS ring
// (72 KB -> 2 blocks/CU). One barrier + counted vmcnt(3) per K-tile.
// K/V stored HEAD-MAJOR [b][h][n][64] so k_attnA reads contiguous 128B rows.
// r12: epilogue routes each wave's 64x64 tile through its PRIVATE LDS region
// (64 rows x 136B; +8B pad -> <=2-way read conflicts = free) so global
// stores are 8x128B fully dense lines (was 32B fragments strided 128B,
// WRITE_SIZE 113MB vs 96MB ideal).
__global__ void __launch_bounds__(512) k_kvgemm(const u16* __restrict__ Xb,
    const u16* __restrict__ TK, const u16* __restrict__ TV,
    const void* __restrict__ bk, const void* __restrict__ bv,
    u16* __restrict__ Kb, u16* __restrict__ Vb,
    const int* __restrict__ nidx, const int* __restrict__ cntc,
    int tlo, int s, int nt, const int* __restrict__ flagp){
  int f32 = *flagp;
  int orig = blockIdx.x;
  int x = orig & 7, r = orig >> 3;
  int bx = r / nt, pr = r - bx*nt;
  int pairg = x*nt + pr;                 // [0, 8*nt)
  int by = pairg & 3; int kvti = pairg >> 2; int kv = kvti & 1; int ti = kvti >> 1;
  int b = bx >> 4, jt = bx & 15;
  int cnt = cntc[b];
  if (jt*256 >= cnt) return;             // uniform early exit
  int c = 2*(tlo+ti)+s;
  size_t boff = (size_t)c*DD;
  const u16* WT = (kv ? TV : TK) + (size_t)ti*FF*DD;
  const void* bias = kv ? bv : bk;
  u16* out = (kv ? Vb : Kb) + (size_t)ti*((size_t)NB*NN*DD);
  int n0 = by*128;
  __shared__ __align__(16) char LDS[3*24576];
  int tid = threadIdx.x, wid = tid >> 6, lane = tid & 63;
  int wr = wid >> 1, wcn = wid & 1;
  const u16* gp0; const u16* gp1; const u16* gp2;
  int lo0, lo1, lo2;
  {
    const u16* gps[3]; int los[3];
    #pragma unroll
    for (int i = 0; i < 3; ++i){
      int e = tid + i*512;
      if (e < 1024){                      // A segs
        int row = e>>2, sp = e&3;
        int ssrc = sp ^ (((row>>3)&1)<<1);
        int cl = jt*256 + row; if (cl >= cnt) cl = cnt-1;
        int grow = nidx[b*NN + cl];
        gps[i] = Xb + ((size_t)b*NN + grow)*FF + ssrc*8;
        los[i] = e*16;
      } else {                            // B segs
        int e2 = e - 1024;
        int row = e2>>2, sp = e2&3;
        int ssrc = sp ^ (((row>>3)&1)<<1);
        gps[i] = WT + (size_t)(n0 + row)*FF + ssrc*8;
        los[i] = 16384 + e2*16;
      }
    }
    gp0=gps[0]; gp1=gps[1]; gp2=gps[2];
    lo0=los[0]; lo1=los[1]; lo2=los[2];
  }
#define STAGE(T) { char* bb_ = LDS + ((T)%3)*24576; \
  glds16(gp0 + (T)*32, bb_ + lo0); glds16(gp1 + (T)*32, bb_ + lo1); \
  glds16(gp2 + (T)*32, bb_ + lo2); }
  int ke = (lane>>4) ^ (((lane>>3)&1)<<1);
  int arow[4], brow[4];
  #pragma unroll
  for (int mi = 0; mi < 4; ++mi)
    arow[mi] = (wr*64 + mi*16 + (lane&15))*64 + ke*16;
  #pragma unroll
  for (int ni = 0; ni < 4; ++ni)
    brow[ni] = 16384 + (wcn*64 + ni*16 + (lane&15))*64 + ke*16;
  f32x4 acc[4][4] = {};
  STAGE(0);
  STAGE(1);
  asm volatile("s_waitcnt vmcnt(3)" ::: "memory");
  __builtin_amdgcn_sched_barrier(0);
  __builtin_amdgcn_s_barrier();
  __builtin_amdgcn_sched_barrier(0);
  #pragma unroll
  for (int t = 0; t < 32; ++t){
    const char* Bbuf = LDS + (t%3)*24576;
    short8v af[4], bf[4];
    #pragma unroll
    for (int mi = 0; mi < 4; ++mi)
      af[mi] = *(const short8v*)(Bbuf + arow[mi]);
    #pragma unroll
    for (int ni = 0; ni < 4; ++ni)
      bf[ni] = *(const short8v*)(Bbuf + brow[ni]);
    if (t + 2 <= 31) STAGE(t+2);           // buf (t+2)%3: disjoint from t, t+1
    __builtin_amdgcn_s_setprio(1);
    #pragma unroll
    for (int mi = 0; mi < 4; ++mi)
      #pragma unroll
      for (int ni = 0; ni < 4; ++ni)
        acc[mi][ni] = __builtin_amdgcn_mfma_f32_16x16x32_bf16(af[mi], bf[ni], acc[mi][ni], 0, 0, 0);
    __builtin_amdgcn_s_setprio(0);
    if (t < 30)       asm volatile("s_waitcnt vmcnt(3)" ::: "memory");
    else if (t == 30) asm volatile("s_waitcnt vmcnt(0)" ::: "memory");
    __builtin_amdgcn_sched_barrier(0);
    if (t < 31){
      __builtin_amdgcn_s_barrier();
      __builtin_amdgcn_sched_barrier(0);
    }
  }
#undef STAGE
  // ---- epilogue: wave-private LDS transpose -> dense 1KB stores ----
  __syncthreads();                      // all ring reads done; reuse LDS
  u16* Lw = (u16*)LDS + wid*(64*68);    // 64 rows x 68 u16 (136B stride)
  int q4 = lane >> 4, l15 = lane & 15;
  #pragma unroll
  for (int mi = 0; mi < 4; ++mi){
    #pragma unroll
    for (int ni = 0; ni < 4; ++ni){
      int col = n0 + wcn*64 + ni*16 + l15;
      float bvf = ldf(bias, boff + col, f32);
      #pragma unroll
      for (int r2 = 0; r2 < 4; ++r2){
        int rl = mi*16 + q4*4 + r2;
        Lw[rl*68 + ni*16 + l15] = f2bf(acc[mi][ni][r2] + bvf);
      }
    }
  }
  // wave-private region: only need this wave's ds_writes visible (lgkm waits
  // inserted by compiler before dependent ds_reads)
  {
    int row0g = jt*256 + wr*64;
    int colg0 = n0 + wcn*64 + (lane&7)*8;
    int hg = colg0 >> 6, dhg = colg0 & 63;
    #pragma unroll
    for (int ps = 0; ps < 8; ++ps){
      int rl = ps*8 + (lane>>3);
      u16x8 v = *(u16x8*)&Lw[rl*68 + (lane&7)*8];
      int row = row0g + rl;
      *(u16x8*)&out[(((size_t)(b*HH + hg))*NN + row)*DH + dhg] = v;
    }
  }
}

// standalone q projection + per-head LN (first stage of each tlo batch)
__global__ void __launch_bounds__(512) k_qproj(const float* __restrict__ qstate,
      const void* __restrict__ Wq, const void* __restrict__ bq,
      float* __restrict__ qh, int tlo, int s, int wmode,
      const int* __restrict__ flagp){
  int f32 = *flagp;
  int wf32 = wmode ? f32 : 0;
  int z = blockIdx.x; int ti = z >> 5, rr = z & 31;
  int b = rr >> 3, p = rr & 7;
  int t = tlo + ti, c = 2*t + s;
  size_t woff = (size_t)c*DD*DD, boff = (size_t)c*DD;
  int d = threadIdx.x;
  __shared__ float xs[DD];
  __shared__ float red[4096];
  const float* xrow = qstate + (((size_t)(b*TT+t))*PP + p)*DD;
  xs[d] = xrow[d];
  __syncthreads();
  float acc = ldf(bq, boff + d, f32) + gemv_vec(xs, Wq, woff, DD, wf32, red, d);
  float s1 = wave_sum(acc) * (1.f/DH);
  float s2 = wave_sum(acc*acc) * (1.f/DH);
  float var = s2 - s1*s1;
  qh[(size_t)z*DD + d] = (acc - s1) * rsqrtf(var + 1e-5f);
}

// attention partials over COMPACTED keys. K/V are HEAD-MAJOR [b][h][n][64].
// K not LDS-staged (single use, coalesced); V staged (64x reuse). LDS 44KB.
__global__ void __launch_bounds__(512) k_attnA(const u16* __restrict__ Kb,
     const u16* __restrict__ Vb, const float* __restrict__ qh,
     const int* __restrict__ cntc, float* __restrict__ Opart, float* __restrict__ lpart){
  int ic = blockIdx.x, bh = blockIdx.y, ti = blockIdx.z;
  int b = bh >> 3, h = bh & 7;
  int cnt = cntc[b];
  if (ic*CHK >= cnt) return;              // uniform early exit (pre-barrier)
  int tid = threadIdx.x, p8 = tid >> 6, ln = tid & 63;
  int r8 = ln >> 3, g = ln & 7;
  __shared__ __align__(16) char KV[32768];   // Vs only [256r][128B]
  __shared__ float qs[PP*DH];
  __shared__ float qsum[PP];
  __shared__ float e_lds[CHK*9];
  int rem = cnt - ic*CHK;                 // >=1 here
  float qv = qh[((size_t)(ti*32 + b*PP + p8))*DD + h*DH + ln];
  size_t tioff = (size_t)ti*((size_t)NB*NN*DD);
  const u16* Kbase = Kb + tioff + ((size_t)(b*HH + h)*NN + (size_t)ic*CHK)*DH;
  const u16* Vbase = Vb + tioff + ((size_t)(b*HH + h)*NN + (size_t)ic*CHK)*DH;
  #pragma unroll
  for (int i = 0; i < 4; ++i){
    int e = tid + i*512;
    int row = e >> 3, sp = e & 7;
    int ss = sp ^ (row & 7);
    int rr = row < rem ? row : rem-1;
    glds16(Vbase + (size_t)rr*DH + ss*8, (char*)KV + e*16);
  }
  qs[p8*DH + ln] = qv;
  {
    float sQ = wave_sum(qv);
    if (ln == 0) qsum[p8] = sQ;
  }
  asm volatile("s_waitcnt lgkmcnt(0)" ::: "memory");
  __builtin_amdgcn_sched_barrier(0);
  __builtin_amdgcn_s_barrier();
  __builtin_amdgcn_sched_barrier(0);
  #pragma unroll
  for (int it = 0; it < CHK/64; ++it){
    int nl = it*64 + p8*8 + r8;
    int rr8 = nl < rem ? nl : rem-1;
    u16x8 kv8 = *(const u16x8*)(Kbase + (size_t)rr8*DH + g*8);   // direct, coalesced
    float kf[8];
    #pragma unroll
    for (int e = 0; e < 8; ++e) kf[e] = bf2f(kv8[e]);
    float sm = 0, sq = 0;
    #pragma unroll
    for (int e = 0; e < 8; ++e){ sm += kf[e]; sq += kf[e]*kf[e]; }
    #pragma unroll
    for (int o = 1; o < 8; o <<= 1){
      sm += __shfl_xor(sm, o);
      sq += __shfl_xor(sq, o);
    }
    sm *= (1.f/DH); sq = sq*(1.f/DH) - sm*sm;
    float inv = rsqrtf(sq + 1e-5f);
    float ap[8];
    #pragma unroll
    for (int p = 0; p < 8; ++p){
      f32x4 qa = *(const f32x4*)&qs[p*DH + g*8];
      f32x4 qb = *(const f32x4*)&qs[p*DH + g*8 + 4];
      ap[p] = kf[0]*qa.x + kf[1]*qa.y + kf[2]*qa.z + kf[3]*qa.w
            + kf[4]*qb.x + kf[5]*qb.y + kf[6]*qb.z + kf[7]*qb.w;
    }
    #pragma unroll
    for (int o = 1; o < 8; o <<= 1){
      #pragma unroll
      for (int p = 0; p < 8; ++p) ap[p] += __shfl_xor(ap[p], o);
    }
    float dg = (g==0)?ap[0]:(g==1)?ap[1]:(g==2)?ap[2]:(g==3)?ap[3]
             : (g==4)?ap[4]:(g==5)?ap[5]:(g==6)?ap[6]:ap[7];
    float sv = (dg - sm*qsum[g]) * inv * 0.125f;
    e_lds[nl*9 + g] = (nl < rem) ? __expf(sv) : 0.f;
  }
  __syncthreads();   // drains vmcnt(0): V staged; e_lds visible cross-wave
  {
    float lp = 0;
    #pragma unroll
    for (int j = 0; j < CHK/64; ++j) lp += e_lds[(ln + j*64)*9 + p8];
    lp = wave_sum(lp);
    if (ln == 0) lpart[((size_t)(ti*32+bh)*NCH + ic)*PP + p8] = lp;
  }
  {
    float a0=0,a1=0,a2=0,a3=0,a4=0,a5=0,a6=0,a7=0;
    int vseg = (r8 ^ g) * 16;
    #pragma unroll 4
    for (int m = 0; m < CHK/8; ++m){
      float e = e_lds[(g + m*8)*9 + p8];
      u16x8 vv = *(const u16x8*)((const char*)KV + (g + m*8)*128 + vseg);
      a0 += e*bf2f(vv[0]); a1 += e*bf2f(vv[1]);
      a2 += e*bf2f(vv[2]); a3 += e*bf2f(vv[3]);
      a4 += e*bf2f(vv[4]); a5 += e*bf2f(vv[5]);
      a6 += e*bf2f(vv[6]); a7 += e*bf2f(vv[7]);
    }
    #pragma unroll
    for (int o = 1; o < 8; o <<= 1){
      a0 += __shfl_xor(a0, o); a1 += __shfl_xor(a1, o);
      a2 += __shfl_xor(a2, o); a3 += __shfl_xor(a3, o);
      a4 += __shfl_xor(a4, o); a5 += __shfl_xor(a5, o);
      a6 += __shfl_xor(a6, o); a7 += __shfl_xor(a7, o);
    }
    if (g == 0){
      float* op = Opart + ((size_t)(ti*32+bh)*NCH + ic)*512 + p8*64 + r8*8;
      f32x4 lo = {a0,a1,a2,a3}, hi = {a4,a5,a6,a7};
      *(f32x4*)op = lo;
      *((f32x4*)op + 1) = hi;
    }
  }
}

// ---- MFMA tail, b-split (only used if ws fits Wt; r10: slow at small nt).
__global__ void __launch_bounds__(512) k_tailm(
    const float* __restrict__ Opart, const float* __restrict__ lpart,
    const int* __restrict__ cntc,
    float* __restrict__ qstate, float* __restrict__ qh,
    const u16* __restrict__ Wt,
    const void* __restrict__ bo, const void* __restrict__ ag, const void* __restrict__ ab,
    const void* __restrict__ bm1, const void* __restrict__ lg, const void* __restrict__ lb,
    const void* __restrict__ bm2, const void* __restrict__ pg, const void* __restrict__ pb,
    const void* __restrict__ bq, void* __restrict__ dout,
    int tlo, int s, int nt, const int* __restrict__ flagp){
  int f32 = *flagp;
  int ti = blockIdx.x & 7, b = blockIdx.x >> 3;
  if (ti >= nt) return;
  int t = tlo + ti, c = 2*t + s;
  int tid = threadIdx.x;
  int w = tid >> 6, lane = tid & 63, q4 = lane >> 4, l15 = lane & 15;
  int n0w = w*64;
  size_t boff = (size_t)c*DD;
  const size_t famSz = (size_t)LL*DD*DD;
  __shared__ u16 As[16*520];
  __shared__ float red1[128], red2[128];
  __shared__ float lval[64];
  int nch = (cntc[b] + CHK - 1) / CHK;
  for (int i = tid; i < 16*520; i += 512) As[i] = 0;
  if (tid < 64){
    int p = tid >> 3, hh = tid & 7;
    float l = 0;
    for (int ic = 0; ic < nch; ++ic)
      l += lpart[((size_t)(ti*32 + b*8 + hh)*NCH + ic)*PP + p];
    lval[tid] = 1.f / l;
  }
  __syncthreads();
  {
    int hh = tid >> 6, dd = tid & 63;
    #pragma unroll
    for (int p = 0; p < 8; ++p){
      float o = 0;
      for (int ic = 0; ic < nch; ++ic)
        o += Opart[((size_t)(ti*32 + b*8 + hh)*NCH + ic)*512 + p*64 + dd];
      As[p*520 + hh*64 + dd] = f2bf(o * lval[p*8 + hh]);
    }
  }
  __syncthreads();
  f32x4 acc[4], q2[4];
  float mv[4], rv[4];
  size_t qoffb = ((size_t)(b*TT+t))*PP*DD;
  {
    const u16* Bp = Wt + famSz + (size_t)c*DD*DD;
    tail_gemm8(acc, Bp, As, l15, q4, n0w);
    #pragma unroll
    for (int ni = 0; ni < 4; ++ni){
      float bv = ldf(bo, boff + n0w + ni*16 + l15, f32);
      #pragma unroll
      for (int r = 0; r < 4; ++r) acc[ni][r] += bv;
    }
    row_ln8(acc, red1, red2, w, l15, q4, mv, rv);
    #pragma unroll
    for (int ni = 0; ni < 4; ++ni){
      int col = n0w + ni*16 + l15;
      float gm = ldf(ag, boff + col, f32), bt = ldf(ab, boff + col, f32);
      #pragma unroll
      for (int r = 0; r < 4; ++r){
        int row = q4*4 + r;
        float y = (acc[ni][r] - mv[r])*rv[r]*gm + bt;
        float res = (q4 < 2) ? qstate[qoffb + (size_t)row*DD + col] : 0.f;
        q2[ni][r] = res + y;
      }
    }
    if (q4 < 2){
      #pragma unroll
      for (int r = 0; r < 4; ++r){
        int row = q4*4 + r;
        #pragma unroll
        for (int ni = 0; ni < 4; ++ni)
          As[row*520 + n0w + ni*16 + l15] = f2bf(q2[ni][r]);
      }
    }
  }
  __syncthreads();
  {
    const u16* Bp = Wt + 2*famSz + (size_t)c*DD*DD;
    tail_gemm8(acc, Bp, As, l15, q4, n0w);
    #pragma unroll
    for (int ni = 0; ni < 4; ++ni){
      float bv = ldf(bm1, boff + n0w + ni*16 + l15, f32);
      #pragma unroll
      for (int r = 0; r < 4; ++r) acc[ni][r] += bv;
    }
    row_ln8(acc, red1, red2, w, l15, q4, mv, rv);
    #pragma unroll
    for (int ni = 0; ni < 4; ++ni){
      int col = n0w + ni*16 + l15;
      float gm = ldf(lg, boff + col, f32), bt = ldf(lb, boff + col, f32);
      #pragma unroll
      for (int r = 0; r < 4; ++r){
        int row = q4*4 + r;
        float y = (acc[ni][r] - mv[r])*rv[r]*gm + bt;
        y = 0.5f*y*(1.f + erff(y*0.70710678118654752f));
        if (q4 < 2) As[row*520 + col] = f2bf(y);
      }
    }
  }
  __syncthreads();
  {
    const u16* Bp = Wt + 3*famSz + (size_t)c*DD*DD;
    tail_gemm8(acc, Bp, As, l15, q4, n0w);
    #pragma unroll
    for (int ni = 0; ni < 4; ++ni){
      float bv = ldf(bm2, boff + n0w + ni*16 + l15, f32);
      #pragma unroll
      for (int r = 0; r < 4; ++r) acc[ni][r] += bv;
    }
    row_ln8(acc, red1, red2, w, l15, q4, mv, rv);
    #pragma unroll
    for (int ni = 0; ni < 4; ++ni){
      int col = n0w + ni*16 + l15;
      float gm = ldf(pg, boff + col, f32), bt = ldf(pb, boff + col, f32);
      #pragma unroll
      for (int r = 0; r < 4; ++r){
        int row = q4*4 + r;
        float outv = q2[ni][r] + (acc[ni][r] - mv[r])*rv[r]*gm + bt;
        if (q4 < 2){
          qstate[qoffb + (size_t)row*DD + col] = outv;
          if (s == 0) As[row*520 + col] = f2bf(outv);
          else {
            if (f32) ((float*)dout)[qoffb + (size_t)row*DD + col] = outv;
            else     ((u16*)dout)[qoffb + (size_t)row*DD + col] = f2bf(outv);
          }
        }
      }
    }
  }
  if (s == 0){
    __syncthreads();
    const u16* Bp = Wt + (size_t)(c+1)*DD*DD;
    tail_gemm8(acc, Bp, As, l15, q4, n0w);
    #pragma unroll
    for (int ni = 0; ni < 4; ++ni){
      float bv = ldf(bq, (size_t)(c+1)*DD + n0w + ni*16 + l15, f32);
      #pragma unroll
      for (int r = 0; r < 4; ++r) acc[ni][r] += bv;
    }
    float s1[4], s2[4];
    #pragma unroll
    for (int r = 0; r < 4; ++r){
      float a0=acc[0][r], a1=acc[1][r], a2=acc[2][r], a3=acc[3][r];
      s1[r] = (a0+a1)+(a2+a3);
      s2[r] = (a0*a0+a1*a1)+(a2*a2+a3*a3);
    }
    #pragma unroll
    for (int o = 1; o < 16; o <<= 1)
      #pragma unroll
      for (int r = 0; r < 4; ++r){
        s1[r] += __shfl_xor(s1[r], o);
        s2[r] += __shfl_xor(s2[r], o);
      }
    if (q4 < 2){
      #pragma unroll
      for (int r = 0; r < 4; ++r){
        int row = q4*4 + r;
        float m = s1[r] * (1.f/DH);
        float var = s2[r] * (1.f/DH) - m*m;
        float ri = rsqrtf(var + 1e-5f);
        #pragma unroll
        for (int ni = 0; ni < 4; ++ni){
          int col = n0w + ni*16 + l15;
          qh[((size_t)(ti*32 + b*8 + row))*DD + col] = (acc[ni][r] - m)*ri;
        }
      }
    }
  }
}

// GEMV tail (primary path at 256MiB ws)
__global__ void __launch_bounds__(512) k_tail(
    const float* __restrict__ Opart, const float* __restrict__ lpart,
    const int* __restrict__ cntc,
    float* __restrict__ qstate, float* __restrict__ qh,
    const void* __restrict__ Wo_, const void* __restrict__ Wm1_,
    const void* __restrict__ Wm2_, const void* __restrict__ Wq_,
    const void* __restrict__ bo, const void* __restrict__ ag, const void* __restrict__ ab,
    const void* __restrict__ bm1, const void* __restrict__ lg, const void* __restrict__ lb,
    const void* __restrict__ bm2, const void* __restrict__ pg, const void* __restrict__ pb,
    const void* __restrict__ bq,
    int tlo, int s, int wmode, const int* __restrict__ flagp){
  int f32 = *flagp;
  int wf32 = wmode ? f32 : 0;
  int z = blockIdx.x; int ti = z >> 5, rr = z & 31;
  int b = rr >> 3, p = rr & 7;
  int t = tlo + ti, c = 2*t + s;
  int d = threadIdx.x;
  int h = d >> 6, dd = d & 63;
  int lane = d & 63, wid = d >> 6;
  size_t qoff = (((size_t)(b*TT+t))*PP + p)*DD;
  size_t boff = (size_t)c*DD;
  size_t w0 = (size_t)c*DD*DD;
  __shared__ float xs[DD];
  __shared__ float red[4096];
  __shared__ float r1[8], r2[8];
  int nch = (cntc[b] + CHK - 1) / CHK;
  float o = 0, l = 0;
  for (int ic = 0; ic < nch; ++ic){
    o += Opart[((size_t)(ti*32 + b*8 + h)*NCH + ic)*512 + p*64 + dd];
    l += lpart[((size_t)(ti*32 + b*8 + h)*NCH + ic)*PP + p];
  }
  float upd = o / l;
  xs[d] = upd;
  __syncthreads();
  float acc = ldf(bo, boff + d, f32) + gemv_vec(xs, Wo_, w0, DD, wf32, red, d);
  {
    float s1 = wave_sum(acc), s2 = wave_sum(acc*acc);
    if (lane == 0){ r1[wid] = s1; r2[wid] = s2; }
  }
  __syncthreads();
  float m = 0, qv = 0;
  #pragma unroll
  for (int i = 0; i < 8; ++i){ m += r1[i]; qv += r2[i]; }
  m *= (1.f/DD); float var = qv*(1.f/DD) - m*m;
  float y = (acc - m)*rsqrtf(var + 1e-5f)*ldf(ag, boff+d, f32) + ldf(ab, boff+d, f32);
  float q2 = qstate[qoff + d] + y;
  __syncthreads();
  xs[d] = q2;
  __syncthreads();
  float acc2 = ldf(bm1, boff + d, f32) + gemv_vec(xs, Wm1_, w0, DD, wf32, red, d);
  {
    float s1 = wave_sum(acc2), s2 = wave_sum(acc2*acc2);
    if (lane == 0){ r1[wid] = s1; r2[wid] = s2; }
  }
  __syncthreads();
  m = 0; qv = 0;
  #pragma unroll
  for (int i = 0; i < 8; ++i){ m += r1[i]; qv += r2[i]; }
  m *= (1.f/DD); var = qv*(1.f/DD) - m*m;
  float y2 = (acc2 - m)*rsqrtf(var + 1e-5f)*ldf(lg, boff+d, f32) + ldf(lb, boff+d, f32);
  y2 = 0.5f*y2*(1.f + erff(y2*0.70710678118654752f));
  __syncthreads();
  xs[d] = y2;
  __syncthreads();
  float acc3 = ldf(bm2, boff + d, f32) + gemv_vec(xs, Wm2_, w0, DD, wf32, red, d);
  {
    float s1 = wave_sum(acc3), s2 = wave_sum(acc3*acc3);
    if (lane == 0){ r1[wid] = s1; r2[wid] = s2; }
  }
  __syncthreads();
  m = 0; qv = 0;
  #pragma unroll
  for (int i = 0; i < 8; ++i){ m += r1[i]; qv += r2[i]; }
  m *= (1.f/DD); var = qv*(1.f/DD) - m*m;
  float y3 = (acc3 - m)*rsqrtf(var + 1e-5f)*ldf(pg, boff+d, f32) + ldf(pb, boff+d, f32);
  float outv = q2 + y3;
  qstate[qoff + d] = outv;
  if (s == 0){
    __syncthreads();
    xs[d] = outv;
    __syncthreads();
    size_t w1 = (size_t)(c+1)*DD*DD;
    float accq = ldf(bq, (size_t)(c+1)*DD + d, f32) + gemv_vec(xs, Wq_, w1, DD, wf32, red, d);
    float t1 = wave_sum(accq) * (1.f/DH);
    float t2 = wave_sum(accq*accq) * (1.f/DH);
    float var2 = t2 - t1*t1;
    qh[(size_t)z*DD + d] = (accq - t1) * rsqrtf(var2 + 1e-5f);
  }
}

__global__ void k_out(const float* __restrict__ qstate, void* __restrict__ dout,
                      const int* __restrict__ flagp){
  int f32 = *flagp;
  int i = blockIdx.x*256 + threadIdx.x;
  if (f32) ((float*)dout)[i] = qstate[i];
  else     ((u16*)dout)[i] = f2bf(qstate[i]);
}

extern "C" void kernel_launch(void* const* d_in, const int* in_sizes, int n_in,
                              void* d_out, int out_size, void* d_ws, size_t ws_size,
                              hipStream_t stream){
  (void)in_sizes; (void)n_in; (void)out_size;
  const void* X   = d_in[0];
  const int* bm    = (const int*)d_in[1];
  const int* ntype = (const int*)d_in[2];
  const void* pmW = d_in[3];  const void* pmb = d_in[4];
  const void* pmg = d_in[5];  const void* pmbn= d_in[6];
  const void* lsig= d_in[7];  const void* rmul= d_in[8];
  const void* Wq  = d_in[9];  const void* bq  = d_in[10];
  const void* Wk  = d_in[11]; const void* bk  = d_in[12];
  const void* Wv  = d_in[13]; const void* bv  = d_in[14];
  const void* Wo  = d_in[15]; const void* bo  = d_in[16];
  const void* ag  = d_in[17]; const void* ab  = d_in[18];
  const void* Wm1 = d_in[19]; const void* bm1 = d_in[20];
  const void* lg  = d_in[21]; const void* lb  = d_in[22];
  const void* Wm2 = d_in[23]; const void* bm2 = d_in[24];
  const void* pg  = d_in[25]; const void* pb  = d_in[26];

  char* ws = (char*)d_ws;
  int*   flagp    = (int*)(ws + 0);
  float* cnt      = (float*)(ws + 256);
  float* bmsum    = (float*)(ws + 512);
  float* colsums  = (float*)(ws + 768);
  float* coltotal = (float*)(ws + 99072);
  float* qstate   = (float*)(ws + 279296);
  int*   cntc     = (int*)(ws + 672512);     // 16 B (pad 256)
  int*   nidx     = (int*)(ws + 672768);     // 64 KB

  size_t off = 738304;
  auto take = [&](size_t bytes)->char*{
    char* p = ws + off; off = (off + bytes + 255) & ~(size_t)255; return p;
  };
  u16* Xbf = (u16*)take((size_t)NB*NN*FF*2);   // 32 MiB bf16 copy of X

  const size_t perT = (size_t)65536           // qh
                    + 16384                   // lpart (NCH=16)
                    + 1048576                 // Opart (NCH=16)
                    + 2*1048576               // WkT, WvT
                    + 2*16777216;             // Kb, Vb
  const size_t wtBytes = (size_t)4*LL*DD*DD*2;      // 25.2 MB
  const size_t pmwbB   = (size_t)FF*DD*2;           // 1 MB
  const size_t wqbB    = (size_t)LL*DD*DD*2;        // 6.3 MB
  size_t base = off;

  int nt = 1;
  if      (ws_size >= base + 6*perT + 65536) nt = 6;
  else if (ws_size >= base + 3*perT + 65536) nt = 3;
  else if (ws_size >= base + 2*perT + 65536) nt = 2;

  float* qh    = (float*)take((size_t)nt*65536);
  float* lpart = (float*)take((size_t)nt*16384);
  float* Opart = (float*)take((size_t)nt*1048576);
  u16*   WkT   = (u16*)take((size_t)nt*1048576);
  u16*   WvT   = (u16*)take((size_t)nt*1048576);
  u16*   Kb    = (u16*)take((size_t)nt*16777216);
  u16*   Vb    = (u16*)take((size_t)nt*16777216);

  int useWt = (ws_size >= off + wtBytes + 65536) ? 1 : 0;
  u16* Wt = useWt ? (u16*)take(wtBytes) : nullptr;
  int useCvt = (ws_size >= off + pmwbB + wqbB + 65536) ? 1 : 0;
  u16* pmWb = useCvt ? (u16*)take(pmwbB) : nullptr;
  u16* Wqb  = useCvt ? (u16*)take(wqbB)  : nullptr;

  const void* WqG = useCvt ? (const void*)Wqb : Wq;
  int wmode = useCvt ? 0 : 1;

  // k_xcv partial buffers carved from Kb (first written by kvgemm, which runs
  // after k_fold/k_mu consumed them -> stream-safe). 14.7 MB <= Kb nt>=1.
  float* Pcol = (float*)Kb;                                  // NXB*NB*TT*FF f32
  float* Ptot = (float*)((char*)Kb + (size_t)NXB*NB*TT*FF*4); // NXB*NB*FF f32

  hipMemsetAsync(ws + 256, 0, 512, stream);    // cnt + bmsum
  k_detect<<<1, 256, 0, stream>>>(X, flagp);
  k_compact<<<NB, 256, 0, stream>>>(bm, nidx, cntc);
  if (useWt)
    k_wbfT<<<dim3(16, 16, 4*LL), dim3(32, 8), 0, stream>>>(Wq, Wo, Wm1, Wm2, Wt, flagp);
  if (useCvt){
    const int n0q = (FF*DD)/4;                      // pmW quads
    const int nblk = (FF*DD + LL*DD*DD)/4/256;
    k_cvt2<<<nblk, 256, 0, stream>>>(pmW, pmWb, n0q, Wq, Wqb, flagp);
  }
  k_xcv<<<dim3(NXB, NB), 256, 0, stream>>>(X, Xbf, bm, ntype, Pcol, Ptot,
                                           cnt, bmsum, flagp);
  k_fold<<<dim3(4, NB*TT), 256, 0, stream>>>(Pcol, Ptot, colsums, coltotal);
  if (useCvt)
    k_mu<<<NB*TT, 512, 0, stream>>>(colsums, coltotal, cnt, bmsum,
        pmWb, pmb, pmg, pmbn, lsig, rmul, qstate, d_out, 0, flagp);
  else
    k_mu<<<NB*TT, 512, 0, stream>>>(colsums, coltotal, cnt, bmsum,
        pmW, pmb, pmg, pmbn, lsig, rmul, qstate, d_out, 1, flagp);

  for (int tlo = 0; tlo < TT; tlo += nt){
    for (int s = 0; s < 2; ++s){
      k_transpose<<<dim3(16, 32, 2*nt), dim3(32, 8), 0, stream>>>(
          Wk, Wv, WkT, WvT, tlo, s, flagp);
      k_kvgemm<<<64*8*nt, 512, 0, stream>>>(
          Xbf, WkT, WvT, bk, bv, Kb, Vb, nidx, cntc, tlo, s, nt, flagp);
      if (s == 0)
        k_qproj<<<nt*32, 512, 0, stream>>>(qstate, WqG, bq, qh, tlo, 0, wmode, flagp);
      k_attnA<<<dim3(NCH, 32, nt), 512, 0, stream>>>(Kb, Vb, qh, cntc, Opart, lpart);
      if (useWt)
        k_tailm<<<32, 512, 0, stream>>>(Opart, lpart, cntc, qstate, qh, Wt,
            bo, ag, ab, bm1, lg, lb, bm2, pg, pb, bq, d_out, tlo, s, nt, flagp);
      else
        k_tail<<<nt*32, 512, 0, stream>>>(Opart, lpart, cntc, qstate, qh,
            Wo, Wm1, Wm2, Wq, bo, ag, ab, bm1, lg, lb, bm2, pg, pb, bq,
            tlo, s, 1, flagp);
    }
  }
  if (!useWt)
    k_out<<<NB*TT*PP*DD/256, 256, 0, stream>>>(qstate, d_out, flagp);
}

// Round 13
// 618.982 us; speedup vs baseline: 1.0931x; 1.0931x over previous
//
#include <hip/hip_runtime.h>
#include <hip/hip_bf16.h>
#include <stdint.h>

#define TT 6
#define PP 8
#define HH 8
#define DD 512
#define FF 1024
#define DH 64
#define NB 4
#define NN 4096
#define LL 12
#define NCH 16
#define CHK 256
#define NXB 128   // k_xcv n-blocks (32 rows each)

typedef __attribute__((ext_vector_type(8))) short short8v;
typedef __attribute__((ext_vector_type(4))) float f32x4;
typedef __attribute__((ext_vector_type(4))) unsigned short u16x4;
typedef __attribute__((ext_vector_type(8))) unsigned short u16x8;
typedef unsigned short u16;

__device__ __forceinline__ float bf2f(u16 u){
  union { unsigned int i; float f; } x; x.i = ((unsigned int)u) << 16; return x.f;
}
__device__ __forceinline__ u16 f2bf(float f){
  union { float f; unsigned int i; } x; x.f = f;
  unsigned int r = x.i + 0x7fffu + ((x.i >> 16) & 1u);
  return (u16)(r >> 16);
}
__device__ __forceinline__ float wave_sum(float x){
  #pragma unroll
  for (int o = 32; o > 0; o >>= 1) x += __shfl_xor(x, o);
  return x;
}
__device__ __forceinline__ float ldf(const void* p, size_t i, int f32){
  float v;
  if (f32) v = ((const float*)p)[i];
  else     v = bf2f(((const u16*)p)[i]);
  return v;
}
// Vectorized block GEMV: y[d] = sum_k xs[k]*W[wbase + k*DD + d], d = tid in [0,512).
__device__ __forceinline__ float gemv_vec(const float* __restrict__ xs,
    const void* __restrict__ W, size_t wbase, int ktot, int wf32,
    float* __restrict__ red, int tid){
  int g = tid & 63, sl = tid >> 6;
  int kpw = ktot >> 3;
  float a[8] = {0,0,0,0,0,0,0,0};
  if (wf32){
    const float* Wp = (const float*)W + wbase + (size_t)(sl*kpw)*DD + g*8;
    #pragma unroll 4
    for (int i = 0; i < kpw; ++i){
      float xv = xs[sl*kpw + i];
      f32x4 lo = *(const f32x4*)(Wp + (size_t)i*DD);
      f32x4 hi = *(const f32x4*)(Wp + (size_t)i*DD + 4);
      a[0]+=xv*lo.x; a[1]+=xv*lo.y; a[2]+=xv*lo.z; a[3]+=xv*lo.w;
      a[4]+=xv*hi.x; a[5]+=xv*hi.y; a[6]+=xv*hi.z; a[7]+=xv*hi.w;
    }
  } else {
    const u16* Wp = (const u16*)W + wbase + (size_t)(sl*kpw)*DD + g*8;
    #pragma unroll 4
    for (int i = 0; i < kpw; ++i){
      float xv = xs[sl*kpw + i];
      u16x8 w8 = *(const u16x8*)(Wp + (size_t)i*DD);
      #pragma unroll
      for (int j = 0; j < 8; ++j) a[j] += xv * bf2f(w8[j]);
    }
  }
  #pragma unroll
  for (int j = 0; j < 8; ++j) red[sl*512 + g*8 + j] = a[j];
  __syncthreads();
  float y = 0;
  #pragma unroll
  for (int s2 = 0; s2 < 8; ++s2) y += red[s2*512 + tid];
  return y;
}
// async global->LDS, 16B per lane. Global src IS per-lane (gather/swizzle OK);
// LDS dest must be wave-uniform base + lane*16 (linear).
__device__ __forceinline__ void glds16(const void* g, void* l){
#if __has_builtin(__builtin_amdgcn_global_load_lds)
  __builtin_amdgcn_global_load_lds(
      (const __attribute__((address_space(1))) void*)g,
      (__attribute__((address_space(3))) void*)l, 16, 0, 0);
#else
  *(u16x8*)l = *(const u16x8*)g;
#endif
}
// MFMA tail helpers (b-split tailm): M=16 (8 real rows + 8 zero-pad) x
// N=64-per-wave GEMM, A in LDS [16][520] bf16, B from transposed Wt[d][k].
__device__ __forceinline__ void tail_gemm8(f32x4 acc[4], const u16* __restrict__ Bp,
    const u16* As, int l15, int q4, int n0w){
  #pragma unroll
  for (int ni = 0; ni < 4; ++ni){ f32x4 z = {0,0,0,0}; acc[ni] = z; }
  #pragma unroll 2
  for (int k0 = 0; k0 < 512; k0 += 32){
    short8v bf[4], af;
    #pragma unroll
    for (int ni = 0; ni < 4; ++ni)
      bf[ni] = *(const short8v*)(Bp + (size_t)(n0w + ni*16 + l15)*DD + k0 + q4*8);
    af = *(const short8v*)(As + l15*520 + k0 + q4*8);
    #pragma unroll
    for (int ni = 0; ni < 4; ++ni)
      acc[ni] = __builtin_amdgcn_mfma_f32_16x16x32_bf16(af, bf[ni], acc[ni], 0, 0, 0);
  }
}
__device__ __forceinline__ void row_ln8(const f32x4 acc[4],
    float* red1, float* red2, int w, int l15, int q4,
    float mv[4], float rv[4]){
  float s1[4], s2[4];
  #pragma unroll
  for (int r = 0; r < 4; ++r){
    float a0=acc[0][r], a1=acc[1][r], a2=acc[2][r], a3=acc[3][r];
    s1[r] = (a0+a1)+(a2+a3);
    s2[r] = (a0*a0+a1*a1)+(a2*a2+a3*a3);
  }
  #pragma unroll
  for (int o = 1; o < 16; o <<= 1)
    #pragma unroll
    for (int r = 0; r < 4; ++r){
      s1[r] += __shfl_xor(s1[r], o);
      s2[r] += __shfl_xor(s2[r], o);
    }
  if (l15 == 0){
    #pragma unroll
    for (int r = 0; r < 4; ++r){
      int row = q4*4 + r;
      red1[row*8 + w] = s1[r];
      red2[row*8 + w] = s2[r];
    }
  }
  __syncthreads();
  #pragma unroll
  for (int r = 0; r < 4; ++r){
    int row = q4*4 + r;
    float S1 = 0, S2 = 0;
    #pragma unroll
    for (int j = 0; j < 8; ++j){ S1 += red1[row*8+j]; S2 += red2[row*8+j]; }
    float m = S1 * (1.f/DD);
    float var = S2 * (1.f/DD) - m*m;
    mv[r] = m;
    rv[r] = rsqrtf(var + 1e-5f);
  }
  __syncthreads();
}

// flag=1 -> inputs are float32 ; flag=0 -> inputs are bf16
__global__ void k_detect(const void* __restrict__ X, int* __restrict__ flag){
  int tid = threadIdx.x;
  const u16* u = (const u16*)X;
  int bad = 0;
  for (int i = tid; i < 8192; i += 256){
    int ex = (u[i] >> 7) & 0xFF;
    if (ex >= 0x90) bad = 1;
  }
  __shared__ int s;
  if (tid == 0) s = 0;
  __syncthreads();
  if (bad) s = 1;
  __syncthreads();
  if (tid == 0) *flag = s;
}

// fused dual f32->bf16 (or bf16 copy) converter: array0 quads [0,n0q),
// array1 quads [n0q, ...). One dispatch for pmW + Wq.
__global__ void k_cvt2(const void* __restrict__ s0, u16* __restrict__ d0, int n0q,
                       const void* __restrict__ s1, u16* __restrict__ d1,
                       const int* __restrict__ flagp){
  int f32 = *flagp;
  size_t q = (size_t)blockIdx.x*256 + threadIdx.x;
  const void* s; u16* d; size_t i;
  if (q < (size_t)n0q){ s = s0; d = d0; i = q*4; }
  else                { s = s1; d = d1; i = (q - n0q)*4; }
  if (f32){
    f32x4 v = *(const f32x4*)((const float*)s + i);
    u16x4 o; o.x=f2bf(v.x); o.y=f2bf(v.y); o.z=f2bf(v.z); o.w=f2bf(v.w);
    *(u16x4*)(d+i) = o;
  } else {
    *(u16x4*)(d+i) = *(const u16x4*)((const u16*)s + i);
  }
}

// FUSED X pass: X -> bf16 copy + per-type column PARTIALS (no f32 atomics).
// Partials go to Pcol/Ptot (carved from Kb; kvgemm writes Kb only after k_mu
// consumed them -> stream-safe). cnt/bmsum keep tiny integer atomics (exact).
__global__ void k_xcv(const void* __restrict__ X, u16* __restrict__ Xb,
                      const int* __restrict__ bm, const int* __restrict__ ntype,
                      float* __restrict__ Pcol, float* __restrict__ Ptot,
                      float* __restrict__ cnt, float* __restrict__ bmsum,
                      const int* __restrict__ flagp){
  int f32 = *flagp;
  int b = blockIdx.y, blk = blockIdx.x;
  int n0 = blk * 32;
  int tid = threadIdx.x;
  int f0 = tid * 4;
  __shared__ int sflag[32];
  __shared__ float scnt[TT+1];
  if (tid < 32) sflag[tid] = 0;
  if (tid < TT+1) scnt[tid] = 0.f;
  __syncthreads();
  float acc[TT][4] = {};
  float tot[4] = {0,0,0,0};
  for (int i = 0; i < 32; ++i){
    int n = n0 + i;
    size_t idx = (size_t)(b*NN+n)*FF + f0;
    u16x4 xb;
    bool a;
    if (f32){
      f32x4 v = *(const f32x4*)((const float*)X + idx);
      xb.x=f2bf(v.x); xb.y=f2bf(v.y); xb.z=f2bf(v.z); xb.w=f2bf(v.w);
      a = (v.x!=0.f)||(v.y!=0.f)||(v.z!=0.f)||(v.w!=0.f);
    } else {
      xb = *(const u16x4*)((const u16*)X + idx);
      a = (bf2f(xb.x)!=0.f)||(bf2f(xb.y)!=0.f)||(bf2f(xb.z)!=0.f)||(bf2f(xb.w)!=0.f);
    }
    *(u16x4*)(Xb+idx) = xb;
    if (a) sflag[i] = 1;
    float vbm = (bm[b*NN+n] != 0) ? 1.f : 0.f;
    int ty = ntype[b*NN+n];
    #pragma unroll
    for (int j = 0; j < 4; ++j){
      float xv = bf2f(xb[j]);
      tot[j] += xv;
      float xvv = xv * vbm;
      #pragma unroll
      for (int t = 0; t < TT; ++t) acc[t][j] += (ty==t) ? xvv : 0.f;
    }
  }
  __syncthreads();
  if (tid < 32){
    int n = n0 + tid;
    if (bm[b*NN+n] != 0){
      if (sflag[tid]) atomicAdd(&scnt[ntype[b*NN+n]], 1.f);
      atomicAdd(&scnt[TT], 1.f);
    }
  }
  size_t pbase = (size_t)blk*NB + b;
  #pragma unroll
  for (int t = 0; t < TT; ++t){
    f32x4 v = {acc[t][0], acc[t][1], acc[t][2], acc[t][3]};
    *(f32x4*)&Pcol[(pbase*TT + t)*FF + f0] = v;
  }
  {
    f32x4 v = {tot[0], tot[1], tot[2], tot[3]};
    *(f32x4*)&Ptot[pbase*FF + f0] = v;
  }
  __syncthreads();
  if (tid < TT) atomicAdd(&cnt[b*TT + tid], scnt[tid]);
  if (tid == TT) atomicAdd(&bmsum[b], scnt[TT]);
}

// fold the NXB partials -> colsums/coltotal (parallel: 96 blocks vs the old
// in-k_mu 24-block serial fold). Same ascending blk add order -> bitwise same.
__global__ void k_fold(const float* __restrict__ Pcol, const float* __restrict__ Ptot,
                       float* __restrict__ colsums, float* __restrict__ coltotal){
  int fb = blockIdx.x;            // 0..3
  int bt = blockIdx.y;            // 0..NB*TT-1
  int b = bt / TT, t = bt % TT;
  int f = fb*256 + threadIdx.x;
  float S = 0.f;
  #pragma unroll 4
  for (int blk = 0; blk < NXB; ++blk)
    S += Pcol[(((size_t)blk*NB + b)*TT + t)*FF + f];
  colsums[(size_t)bt*FF + f] = S;
  if (t == 0){
    float T = 0.f;
    #pragma unroll 4
    for (int blk = 0; blk < NXB; ++blk)
      T += Ptot[((size_t)blk*NB + b)*FF + f];
    coltotal[b*FF + f] = T;
  }
}

// per-batch stable compaction of valid (bm!=0) key indices
__global__ void k_compact(const int* __restrict__ bm, int* __restrict__ nidx,
                          int* __restrict__ cntc){
  int b = blockIdx.x, tid = threadIdx.x;   // 256 threads, 16 entries each
  __shared__ int csum[256];
  __shared__ int pref[257];
  int base = b*NN + tid*16;
  int f[16]; int loc = 0;
  #pragma unroll
  for (int i = 0; i < 16; ++i){ f[i] = (bm[base+i] != 0); loc += f[i]; }
  csum[tid] = loc;
  __syncthreads();
  if (tid == 0){
    pref[0] = 0;
    for (int j = 0; j < 256; ++j) pref[j+1] = pref[j] + csum[j];
  }
  __syncthreads();
  int off = b*NN + pref[tid];
  #pragma unroll
  for (int i = 0; i < 16; ++i){ if (f[i]) nidx[off++] = tid*16 + i; }
  if (tid == 0) cntc[b] = pref[256];
}

// Wq/Wo/Wm1/Wm2 -> TRANSPOSED bf16 Wt[fam][c][d][k]
__global__ void k_wbfT(const void* __restrict__ Wq, const void* __restrict__ Wo,
                       const void* __restrict__ Wm1, const void* __restrict__ Wm2,
                       u16* __restrict__ Wt, const int* __restrict__ flagp){
  int f32 = *flagp;
  int z = blockIdx.z;                 // fam*LL + c
  int fam = z / LL;
  const void* src = (fam==0) ? Wq : (fam==1) ? Wo : (fam==2) ? Wm1 : Wm2;
  size_t sbase = (size_t)(z % LL) * DD * DD;
  __shared__ u16 tile[32][33];
  int d0 = blockIdx.x*32, k0 = blockIdx.y*32;
  int tx = threadIdx.x, ty = threadIdx.y;   // 32x8
  #pragma unroll
  for (int i = 0; i < 4; ++i){
    size_t idx = sbase + (size_t)(k0 + ty + i*8)*DD + d0 + tx;
    u16 v;
    if (f32) v = f2bf(((const float*)src)[idx]);
    else     v = ((const u16*)src)[idx];
    tile[ty + i*8][tx] = v;            // tile[k][d]
  }
  __syncthreads();
  #pragma unroll
  for (int i = 0; i < 4; ++i)
    Wt[((size_t)z*DD + d0 + ty + i*8)*DD + k0 + tx] = tile[tx][ty + i*8];
}

// FUSED proto_mu + mu (folded inputs): writes the proto_mu region of d_out,
// then the pmW GEMV + LN + gelu + expand.
__global__ void __launch_bounds__(512) k_mu(const float* __restrict__ colsums,
   const float* __restrict__ coltotal, const float* __restrict__ cnt,
   const float* __restrict__ bmsum,
   const void* __restrict__ pmWx, const void* __restrict__ pmb,
   const void* __restrict__ pmg, const void* __restrict__ pmbn,
   const void* __restrict__ lsig, const void* __restrict__ rmul,
   float* __restrict__ qstate, void* __restrict__ dout, int wmode,
   const int* __restrict__ flagp){
  int f32 = *flagp;
  int wf32 = wmode ? f32 : 0;
  const size_t OFFP = (size_t)NB*TT*PP*DD;
  int bt = blockIdx.x; int b = bt/TT, t = bt%TT;
  int d = threadIdx.x;
  __shared__ float xs[FF];
  __shared__ float red[4096];
  __shared__ float r1[8], r2[8];
  float cv = cnt[bt];
  float inv = 1.f / fmaxf(cv, 1.f);
  float fbinv = 1.f / bmsum[b];
  #pragma unroll
  for (int h = 0; h < 2; ++h){
    int f = d + h*512;
    float pm = (cv > 0.f) ? colsums[(size_t)bt*FF + f] * inv
                          : coltotal[b*FF + f] * fbinv;
    xs[f] = pm;
    if (f32) ((float*)dout)[OFFP + (size_t)bt*FF + f] = pm;
    else     ((u16*)dout)[OFFP + (size_t)bt*FF + f] = f2bf(pm);
  }
  __syncthreads();
  float acc = ldf(pmb, d, f32) + gemv_vec(xs, pmWx, 0, FF, wf32, red, d);
  int lane = d & 63, wid = d >> 6;
  float s1 = wave_sum(acc), s2 = wave_sum(acc*acc);
  if (lane==0){ r1[wid]=s1; r2[wid]=s2; }
  __syncthreads();
  float m=0, qq=0;
  #pragma unroll
  for (int i=0;i<8;++i){ m+=r1[i]; qq+=r2[i]; }
  m *= (1.f/DD); float var = qq*(1.f/DD) - m*m;
  float y = (acc - m) * rsqrtf(var + 1e-5f) * ldf(pmg, d, f32) + ldf(pmbn, d, f32);
  float mu = 0.5f * y * (1.f + erff(y * 0.70710678118654752f));
  #pragma unroll
  for (int p = 0; p < PP; ++p){
    float rv = ldf(rmul, (size_t)(t*PP+p)*DD + d, f32);
    float ls = ldf(lsig, (size_t)t*DD + d, f32);
    qstate[(((size_t)(b*TT+t))*PP + p)*DD + d] = mu + expf(ls) * rv;
  }
}

// batched transpose: z = ti*2 + kv ; layer c = 2*(tlo+ti)+s
__global__ void k_transpose(const void* __restrict__ Wk, const void* __restrict__ Wv,
                            u16* __restrict__ TK, u16* __restrict__ TV,
                            int tlo, int s, const int* __restrict__ flagp){
  int f32 = *flagp;
  int ti = blockIdx.z >> 1, kv = blockIdx.z & 1;
  int c = 2*(tlo+ti)+s;
  size_t eoff = (size_t)c*FF*DD;
  const void* W = kv ? Wv : Wk;
  u16* T = (kv ? TV : TK) + (size_t)ti*FF*DD;
  __shared__ u16 tile[32][33];
  int n0 = blockIdx.x * 32, k0 = blockIdx.y * 32;
  int tx = threadIdx.x, ty = threadIdx.y;
  #pragma unroll
  for (int i = 0; i < 4; ++i){
    size_t idx = eoff + (size_t)(k0 + ty + i*8)*DD + n0 + tx;
    u16 v;
    if (f32) v = f2bf(((const float*)W)[idx]);
    else     v = ((const u16*)W)[idx];
    tile[ty + i*8][tx] = v;
  }
  __syncthreads();
  #pragma unroll
  for (int i = 0; i < 4; ++i)
    T[(size_t)(n0 + ty + i*8)*FF + k0 + tx] = tile[tx][ty + i*8];
}

// ---- K/V GEMM: BM=256 x BN=128, BK=32, 512 thr / 8 waves, 3-buffer LDS ring
// (72 KB -> 2 blocks/CU). One barrier + counted vmcnt(3) per K-tile.
// K/V stored HEAD-MAJOR [b][h][n][64] so k_attnA reads contiguous 128B rows.
// r12 lesson: LDS-transpose epilogue for dense stores REGRESSED (+21us each:
// extra barrier + LDS round-trip + occupancy 35->20%); the MFMA-native
// scattered stores are overlap-hidden. This kernel is at its measured best
// in this exact monolithic form (124us) -- DO NOT TOUCH.
__global__ void __launch_bounds__(512) k_kvgemm(const u16* __restrict__ Xb,
    const u16* __restrict__ TK, const u16* __restrict__ TV,
    const void* __restrict__ bk, const void* __restrict__ bv,
    u16* __restrict__ Kb, u16* __restrict__ Vb,
    const int* __restrict__ nidx, const int* __restrict__ cntc,
    int tlo, int s, int nt, const int* __restrict__ flagp){
  int f32 = *flagp;
  int orig = blockIdx.x;
  int x = orig & 7, r = orig >> 3;
  int bx = r / nt, pr = r - bx*nt;
  int pairg = x*nt + pr;                 // [0, 8*nt)
  int by = pairg & 3; int kvti = pairg >> 2; int kv = kvti & 1; int ti = kvti >> 1;
  int b = bx >> 4, jt = bx & 15;
  int cnt = cntc[b];
  if (jt*256 >= cnt) return;             // uniform early exit
  int c = 2*(tlo+ti)+s;
  size_t boff = (size_t)c*DD;
  const u16* WT = (kv ? TV : TK) + (size_t)ti*FF*DD;
  const void* bias = kv ? bv : bk;
  u16* out = (kv ? Vb : Kb) + (size_t)ti*((size_t)NB*NN*DD);
  int n0 = by*128;
  __shared__ __align__(16) char LDS[3*24576];
  int tid = threadIdx.x, wid = tid >> 6, lane = tid & 63;
  int wr = wid >> 1, wcn = wid & 1;
  const u16* gp0; const u16* gp1; const u16* gp2;
  int lo0, lo1, lo2;
  {
    const u16* gps[3]; int los[3];
    #pragma unroll
    for (int i = 0; i < 3; ++i){
      int e = tid + i*512;
      if (e < 1024){                      // A segs
        int row = e>>2, sp = e&3;
        int ssrc = sp ^ (((row>>3)&1)<<1);
        int cl = jt*256 + row; if (cl >= cnt) cl = cnt-1;
        int grow = nidx[b*NN + cl];
        gps[i] = Xb + ((size_t)b*NN + grow)*FF + ssrc*8;
        los[i] = e*16;
      } else {                            // B segs
        int e2 = e - 1024;
        int row = e2>>2, sp = e2&3;
        int ssrc = sp ^ (((row>>3)&1)<<1);
        gps[i] = WT + (size_t)(n0 + row)*FF + ssrc*8;
        los[i] = 16384 + e2*16;
      }
    }
    gp0=gps[0]; gp1=gps[1]; gp2=gps[2];
    lo0=los[0]; lo1=los[1]; lo2=los[2];
  }
#define STAGE(T) { char* bb_ = LDS + ((T)%3)*24576; \
  glds16(gp0 + (T)*32, bb_ + lo0); glds16(gp1 + (T)*32, bb_ + lo1); \
  glds16(gp2 + (T)*32, bb_ + lo2); }
  int ke = (lane>>4) ^ (((lane>>3)&1)<<1);
  int arow[4], brow[4];
  #pragma unroll
  for (int mi = 0; mi < 4; ++mi)
    arow[mi] = (wr*64 + mi*16 + (lane&15))*64 + ke*16;
  #pragma unroll
  for (int ni = 0; ni < 4; ++ni)
    brow[ni] = 16384 + (wcn*64 + ni*16 + (lane&15))*64 + ke*16;
  f32x4 acc[4][4] = {};
  STAGE(0);
  STAGE(1);
  asm volatile("s_waitcnt vmcnt(3)" ::: "memory");
  __builtin_amdgcn_sched_barrier(0);
  __builtin_amdgcn_s_barrier();
  __builtin_amdgcn_sched_barrier(0);
  #pragma unroll
  for (int t = 0; t < 32; ++t){
    const char* Bbuf = LDS + (t%3)*24576;
    short8v af[4], bf[4];
    #pragma unroll
    for (int mi = 0; mi < 4; ++mi)
      af[mi] = *(const short8v*)(Bbuf + arow[mi]);
    #pragma unroll
    for (int ni = 0; ni < 4; ++ni)
      bf[ni] = *(const short8v*)(Bbuf + brow[ni]);
    if (t + 2 <= 31) STAGE(t+2);           // buf (t+2)%3: disjoint from t, t+1
    __builtin_amdgcn_s_setprio(1);
    #pragma unroll
    for (int mi = 0; mi < 4; ++mi)
      #pragma unroll
      for (int ni = 0; ni < 4; ++ni)
        acc[mi][ni] = __builtin_amdgcn_mfma_f32_16x16x32_bf16(af[mi], bf[ni], acc[mi][ni], 0, 0, 0);
    __builtin_amdgcn_s_setprio(0);
    if (t < 30)       asm volatile("s_waitcnt vmcnt(3)" ::: "memory");
    else if (t == 30) asm volatile("s_waitcnt vmcnt(0)" ::: "memory");
    __builtin_amdgcn_sched_barrier(0);
    if (t < 31){
      __builtin_amdgcn_s_barrier();
      __builtin_amdgcn_sched_barrier(0);
    }
  }
#undef STAGE
  #pragma unroll
  for (int mi = 0; mi < 4; ++mi){
    #pragma unroll
    for (int ni = 0; ni < 4; ++ni){
      int col = n0 + wcn*64 + ni*16 + (lane & 15);
      int h = col >> 6, dh = col & 63;          // head-major store
      float bvf = ldf(bias, boff + col, f32);
      #pragma unroll
      for (int r2 = 0; r2 < 4; ++r2){
        int row = jt*256 + wr*64 + mi*16 + (lane>>4)*4 + r2;   // compact slot
        out[(((size_t)(b*HH + h))*NN + row)*DH + dh] = f2bf(acc[mi][ni][r2] + bvf);
      }
    }
  }
}

// standalone q projection + per-head LN (first stage of each tlo batch)
__global__ void __launch_bounds__(512) k_qproj(const float* __restrict__ qstate,
      const void* __restrict__ Wq, const void* __restrict__ bq,
      float* __restrict__ qh, int tlo, int s, int wmode,
      const int* __restrict__ flagp){
  int f32 = *flagp;
  int wf32 = wmode ? f32 : 0;
  int z = blockIdx.x; int ti = z >> 5, rr = z & 31;
  int b = rr >> 3, p = rr & 7;
  int t = tlo + ti, c = 2*t + s;
  size_t woff = (size_t)c*DD*DD, boff = (size_t)c*DD;
  int d = threadIdx.x;
  __shared__ float xs[DD];
  __shared__ float red[4096];
  const float* xrow = qstate + (((size_t)(b*TT+t))*PP + p)*DD;
  xs[d] = xrow[d];
  __syncthreads();
  float acc = ldf(bq, boff + d, f32) + gemv_vec(xs, Wq, woff, DD, wf32, red, d);
  float s1 = wave_sum(acc) * (1.f/DH);
  float s2 = wave_sum(acc*acc) * (1.f/DH);
  float var = s2 - s1*s1;
  qh[(size_t)z*DD + d] = (acc - s1) * rsqrtf(var + 1e-5f);
}

// attention partials over COMPACTED keys. K/V are HEAD-MAJOR [b][h][n][64].
// K not LDS-staged (single use, coalesced); V staged (64x reuse). LDS 44KB.
__global__ void __launch_bounds__(512) k_attnA(const u16* __restrict__ Kb,
     const u16* __restrict__ Vb, const float* __restrict__ qh,
     const int* __restrict__ cntc, float* __restrict__ Opart, float* __restrict__ lpart){
  int ic = blockIdx.x, bh = blockIdx.y, ti = blockIdx.z;
  int b = bh >> 3, h = bh & 7;
  int cnt = cntc[b];
  if (ic*CHK >= cnt) return;              // uniform early exit (pre-barrier)
  int tid = threadIdx.x, p8 = tid >> 6, ln = tid & 63;
  int r8 = ln >> 3, g = ln & 7;
  __shared__ __align__(16) char KV[32768];   // Vs only [256r][128B]
  __shared__ float qs[PP*DH];
  __shared__ float qsum[PP];
  __shared__ float e_lds[CHK*9];
  int rem = cnt - ic*CHK;                 // >=1 here
  float qv = qh[((size_t)(ti*32 + b*PP + p8))*DD + h*DH + ln];
  size_t tioff = (size_t)ti*((size_t)NB*NN*DD);
  const u16* Kbase = Kb + tioff + ((size_t)(b*HH + h)*NN + (size_t)ic*CHK)*DH;
  const u16* Vbase = Vb + tioff + ((size_t)(b*HH + h)*NN + (size_t)ic*CHK)*DH;
  #pragma unroll
  for (int i = 0; i < 4; ++i){
    int e = tid + i*512;
    int row = e >> 3, sp = e & 7;
    int ss = sp ^ (row & 7);
    int rr = row < rem ? row : rem-1;
    glds16(Vbase + (size_t)rr*DH + ss*8, (char*)KV + e*16);
  }
  qs[p8*DH + ln] = qv;
  {
    float sQ = wave_sum(qv);
    if (ln == 0) qsum[p8] = sQ;
  }
  asm volatile("s_waitcnt lgkmcnt(0)" ::: "memory");
  __builtin_amdgcn_sched_barrier(0);
  __builtin_amdgcn_s_barrier();
  __builtin_amdgcn_sched_barrier(0);
  #pragma unroll
  for (int it = 0; it < CHK/64; ++it){
    int nl = it*64 + p8*8 + r8;
    int rr8 = nl < rem ? nl : rem-1;
    u16x8 kv8 = *(const u16x8*)(Kbase + (size_t)rr8*DH + g*8);   // direct, coalesced
    float kf[8];
    #pragma unroll
    for (int e = 0; e < 8; ++e) kf[e] = bf2f(kv8[e]);
    float sm = 0, sq = 0;
    #pragma unroll
    for (int e = 0; e < 8; ++e){ sm += kf[e]; sq += kf[e]*kf[e]; }
    #pragma unroll
    for (int o = 1; o < 8; o <<= 1){
      sm += __shfl_xor(sm, o);
      sq += __shfl_xor(sq, o);
    }
    sm *= (1.f/DH); sq = sq*(1.f/DH) - sm*sm;
    float inv = rsqrtf(sq + 1e-5f);
    float ap[8];
    #pragma unroll
    for (int p = 0; p < 8; ++p){
      f32x4 qa = *(const f32x4*)&qs[p*DH + g*8];
      f32x4 qb = *(const f32x4*)&qs[p*DH + g*8 + 4];
      ap[p] = kf[0]*qa.x + kf[1]*qa.y + kf[2]*qa.z + kf[3]*qa.w
            + kf[4]*qb.x + kf[5]*qb.y + kf[6]*qb.z + kf[7]*qb.w;
    }
    #pragma unroll
    for (int o = 1; o < 8; o <<= 1){
      #pragma unroll
      for (int p = 0; p < 8; ++p) ap[p] += __shfl_xor(ap[p], o);
    }
    float dg = (g==0)?ap[0]:(g==1)?ap[1]:(g==2)?ap[2]:(g==3)?ap[3]
             : (g==4)?ap[4]:(g==5)?ap[5]:(g==6)?ap[6]:ap[7];
    float sv = (dg - sm*qsum[g]) * inv * 0.125f;
    e_lds[nl*9 + g] = (nl < rem) ? __expf(sv) : 0.f;
  }
  __syncthreads();   // drains vmcnt(0): V staged; e_lds visible cross-wave
  {
    float lp = 0;
    #pragma unroll
    for (int j = 0; j < CHK/64; ++j) lp += e_lds[(ln + j*64)*9 + p8];
    lp = wave_sum(lp);
    if (ln == 0) lpart[((size_t)(ti*32+bh)*NCH + ic)*PP + p8] = lp;
  }
  {
    float a0=0,a1=0,a2=0,a3=0,a4=0,a5=0,a6=0,a7=0;
    int vseg = (r8 ^ g) * 16;
    #pragma unroll 4
    for (int m = 0; m < CHK/8; ++m){
      float e = e_lds[(g + m*8)*9 + p8];
      u16x8 vv = *(const u16x8*)((const char*)KV + (g + m*8)*128 + vseg);
      a0 += e*bf2f(vv[0]); a1 += e*bf2f(vv[1]);
      a2 += e*bf2f(vv[2]); a3 += e*bf2f(vv[3]);
      a4 += e*bf2f(vv[4]); a5 += e*bf2f(vv[5]);
      a6 += e*bf2f(vv[6]); a7 += e*bf2f(vv[7]);
    }
    #pragma unroll
    for (int o = 1; o < 8; o <<= 1){
      a0 += __shfl_xor(a0, o); a1 += __shfl_xor(a1, o);
      a2 += __shfl_xor(a2, o); a3 += __shfl_xor(a3, o);
      a4 += __shfl_xor(a4, o); a5 += __shfl_xor(a5, o);
      a6 += __shfl_xor(a6, o); a7 += __shfl_xor(a7, o);
    }
    if (g == 0){
      float* op = Opart + ((size_t)(ti*32+bh)*NCH + ic)*512 + p8*64 + r8*8;
      f32x4 lo = {a0,a1,a2,a3}, hi = {a4,a5,a6,a7};
      *(f32x4*)op = lo;
      *((f32x4*)op + 1) = hi;
    }
  }
}

// ---- MFMA tail, b-split (only used if ws fits Wt; r10: slow at small nt).
__global__ void __launch_bounds__(512) k_tailm(
    const float* __restrict__ Opart, const float* __restrict__ lpart,
    const int* __restrict__ cntc,
    float* __restrict__ qstate, float* __restrict__ qh,
    const u16* __restrict__ Wt,
    const void* __restrict__ bo, const void* __restrict__ ag, const void* __restrict__ ab,
    const void* __restrict__ bm1, const void* __restrict__ lg, const void* __restrict__ lb,
    const void* __restrict__ bm2, const void* __restrict__ pg, const void* __restrict__ pb,
    const void* __restrict__ bq, void* __restrict__ dout,
    int tlo, int s, int nt, const int* __restrict__ flagp){
  int f32 = *flagp;
  int ti = blockIdx.x & 7, b = blockIdx.x >> 3;
  if (ti >= nt) return;
  int t = tlo + ti, c = 2*t + s;
  int tid = threadIdx.x;
  int w = tid >> 6, lane = tid & 63, q4 = lane >> 4, l15 = lane & 15;
  int n0w = w*64;
  size_t boff = (size_t)c*DD;
  const size_t famSz = (size_t)LL*DD*DD;
  __shared__ u16 As[16*520];
  __shared__ float red1[128], red2[128];
  __shared__ float lval[64];
  int nch = (cntc[b] + CHK - 1) / CHK;
  for (int i = tid; i < 16*520; i += 512) As[i] = 0;
  if (tid < 64){
    int p = tid >> 3, hh = tid & 7;
    float l = 0;
    for (int ic = 0; ic < nch; ++ic)
      l += lpart[((size_t)(ti*32 + b*8 + hh)*NCH + ic)*PP + p];
    lval[tid] = 1.f / l;
  }
  __syncthreads();
  {
    int hh = tid >> 6, dd = tid & 63;
    #pragma unroll
    for (int p = 0; p < 8; ++p){
      float o = 0;
      for (int ic = 0; ic < nch; ++ic)
        o += Opart[((size_t)(ti*32 + b*8 + hh)*NCH + ic)*512 + p*64 + dd];
      As[p*520 + hh*64 + dd] = f2bf(o * lval[p*8 + hh]);
    }
  }
  __syncthreads();
  f32x4 acc[4], q2[4];
  float mv[4], rv[4];
  size_t qoffb = ((size_t)(b*TT+t))*PP*DD;
  {
    const u16* Bp = Wt + famSz + (size_t)c*DD*DD;
    tail_gemm8(acc, Bp, As, l15, q4, n0w);
    #pragma unroll
    for (int ni = 0; ni < 4; ++ni){
      float bv = ldf(bo, boff + n0w + ni*16 + l15, f32);
      #pragma unroll
      for (int r = 0; r < 4; ++r) acc[ni][r] += bv;
    }
    row_ln8(acc, red1, red2, w, l15, q4, mv, rv);
    #pragma unroll
    for (int ni = 0; ni < 4; ++ni){
      int col = n0w + ni*16 + l15;
      float gm = ldf(ag, boff + col, f32), bt = ldf(ab, boff + col, f32);
      #pragma unroll
      for (int r = 0; r < 4; ++r){
        int row = q4*4 + r;
        float y = (acc[ni][r] - mv[r])*rv[r]*gm + bt;
        float res = (q4 < 2) ? qstate[qoffb + (size_t)row*DD + col] : 0.f;
        q2[ni][r] = res + y;
      }
    }
    if (q4 < 2){
      #pragma unroll
      for (int r = 0; r < 4; ++r){
        int row = q4*4 + r;
        #pragma unroll
        for (int ni = 0; ni < 4; ++ni)
          As[row*520 + n0w + ni*16 + l15] = f2bf(q2[ni][r]);
      }
    }
  }
  __syncthreads();
  {
    const u16* Bp = Wt + 2*famSz + (size_t)c*DD*DD;
    tail_gemm8(acc, Bp, As, l15, q4, n0w);
    #pragma unroll
    for (int ni = 0; ni < 4; ++ni){
      float bv = ldf(bm1, boff + n0w + ni*16 + l15, f32);
      #pragma unroll
      for (int r = 0; r < 4; ++r) acc[ni][r] += bv;
    }
    row_ln8(acc, red1, red2, w, l15, q4, mv, rv);
    #pragma unroll
    for (int ni = 0; ni < 4; ++ni){
      int col = n0w + ni*16 + l15;
      float gm = ldf(lg, boff + col, f32), bt = ldf(lb, boff + col, f32);
      #pragma unroll
      for (int r = 0; r < 4; ++r){
        int row = q4*4 + r;
        float y = (acc[ni][r] - mv[r])*rv[r]*gm + bt;
        y = 0.5f*y*(1.f + erff(y*0.70710678118654752f));
        if (q4 < 2) As[row*520 + col] = f2bf(y);
      }
    }
  }
  __syncthreads();
  {
    const u16* Bp = Wt + 3*famSz + (size_t)c*DD*DD;
    tail_gemm8(acc, Bp, As, l15, q4, n0w);
    #pragma unroll
    for (int ni = 0; ni < 4; ++ni){
      float bv = ldf(bm2, boff + n0w + ni*16 + l15, f32);
      #pragma unroll
      for (int r = 0; r < 4; ++r) acc[ni][r] += bv;
    }
    row_ln8(acc, red1, red2, w, l15, q4, mv, rv);
    #pragma unroll
    for (int ni = 0; ni < 4; ++ni){
      int col = n0w + ni*16 + l15;
      float gm = ldf(pg, boff + col, f32), bt = ldf(pb, boff + col, f32);
      #pragma unroll
      for (int r = 0; r < 4; ++r){
        int row = q4*4 + r;
        float outv = q2[ni][r] + (acc[ni][r] - mv[r])*rv[r]*gm + bt;
        if (q4 < 2){
          qstate[qoffb + (size_t)row*DD + col] = outv;
          if (s == 0) As[row*520 + col] = f2bf(outv);
          else {
            if (f32) ((float*)dout)[qoffb + (size_t)row*DD + col] = outv;
            else     ((u16*)dout)[qoffb + (size_t)row*DD + col] = f2bf(outv);
          }
        }
      }
    }
  }
  if (s == 0){
    __syncthreads();
    const u16* Bp = Wt + (size_t)(c+1)*DD*DD;
    tail_gemm8(acc, Bp, As, l15, q4, n0w);
    #pragma unroll
    for (int ni = 0; ni < 4; ++ni){
      float bv = ldf(bq, (size_t)(c+1)*DD + n0w + ni*16 + l15, f32);
      #pragma unroll
      for (int r = 0; r < 4; ++r) acc[ni][r] += bv;
    }
    float s1[4], s2[4];
    #pragma unroll
    for (int r = 0; r < 4; ++r){
      float a0=acc[0][r], a1=acc[1][r], a2=acc[2][r], a3=acc[3][r];
      s1[r] = (a0+a1)+(a2+a3);
      s2[r] = (a0*a0+a1*a1)+(a2*a2+a3*a3);
    }
    #pragma unroll
    for (int o = 1; o < 16; o <<= 1)
      #pragma unroll
      for (int r = 0; r < 4; ++r){
        s1[r] += __shfl_xor(s1[r], o);
        s2[r] += __shfl_xor(s2[r], o);
      }
    if (q4 < 2){
      #pragma unroll
      for (int r = 0; r < 4; ++r){
        int row = q4*4 + r;
        float m = s1[r] * (1.f/DH);
        float var = s2[r] * (1.f/DH) - m*m;
        float ri = rsqrtf(var + 1e-5f);
        #pragma unroll
        for (int ni = 0; ni < 4; ++ni){
          int col = n0w + ni*16 + l15;
          qh[((size_t)(ti*32 + b*8 + row))*DD + col] = (acc[ni][r] - m)*ri;
        }
      }
    }
  }
}

// GEMV tail (primary path at 256MiB ws)
__global__ void __launch_bounds__(512) k_tail(
    const float* __restrict__ Opart, const float* __restrict__ lpart,
    const int* __restrict__ cntc,
    float* __restrict__ qstate, float* __restrict__ qh,
    const void* __restrict__ Wo_, const void* __restrict__ Wm1_,
    const void* __restrict__ Wm2_, const void* __restrict__ Wq_,
    const void* __restrict__ bo, const void* __restrict__ ag, const void* __restrict__ ab,
    const void* __restrict__ bm1, const void* __restrict__ lg, const void* __restrict__ lb,
    const void* __restrict__ bm2, const void* __restrict__ pg, const void* __restrict__ pb,
    const void* __restrict__ bq,
    int tlo, int s, int wmode, const int* __restrict__ flagp){
  int f32 = *flagp;
  int wf32 = wmode ? f32 : 0;
  int z = blockIdx.x; int ti = z >> 5, rr = z & 31;
  int b = rr >> 3, p = rr & 7;
  int t = tlo + ti, c = 2*t + s;
  int d = threadIdx.x;
  int h = d >> 6, dd = d & 63;
  int lane = d & 63, wid = d >> 6;
  size_t qoff = (((size_t)(b*TT+t))*PP + p)*DD;
  size_t boff = (size_t)c*DD;
  size_t w0 = (size_t)c*DD*DD;
  __shared__ float xs[DD];
  __shared__ float red[4096];
  __shared__ float r1[8], r2[8];
  int nch = (cntc[b] + CHK - 1) / CHK;
  float o = 0, l = 0;
  for (int ic = 0; ic < nch; ++ic){
    o += Opart[((size_t)(ti*32 + b*8 + h)*NCH + ic)*512 + p*64 + dd];
    l += lpart[((size_t)(ti*32 + b*8 + h)*NCH + ic)*PP + p];
  }
  float upd = o / l;
  xs[d] = upd;
  __syncthreads();
  float acc = ldf(bo, boff + d, f32) + gemv_vec(xs, Wo_, w0, DD, wf32, red, d);
  {
    float s1 = wave_sum(acc), s2 = wave_sum(acc*acc);
    if (lane == 0){ r1[wid] = s1; r2[wid] = s2; }
  }
  __syncthreads();
  float m = 0, qv = 0;
  #pragma unroll
  for (int i = 0; i < 8; ++i){ m += r1[i]; qv += r2[i]; }
  m *= (1.f/DD); float var = qv*(1.f/DD) - m*m;
  float y = (acc - m)*rsqrtf(var + 1e-5f)*ldf(ag, boff+d, f32) + ldf(ab, boff+d, f32);
  float q2 = qstate[qoff + d] + y;
  __syncthreads();
  xs[d] = q2;
  __syncthreads();
  float acc2 = ldf(bm1, boff + d, f32) + gemv_vec(xs, Wm1_, w0, DD, wf32, red, d);
  {
    float s1 = wave_sum(acc2), s2 = wave_sum(acc2*acc2);
    if (lane == 0){ r1[wid] = s1; r2[wid] = s2; }
  }
  __syncthreads();
  m = 0; qv = 0;
  #pragma unroll
  for (int i = 0; i < 8; ++i){ m += r1[i]; qv += r2[i]; }
  m *= (1.f/DD); var = qv*(1.f/DD) - m*m;
  float y2 = (acc2 - m)*rsqrtf(var + 1e-5f)*ldf(lg, boff+d, f32) + ldf(lb, boff+d, f32);
  y2 = 0.5f*y2*(1.f + erff(y2*0.70710678118654752f));
  __syncthreads();
  xs[d] = y2;
  __syncthreads();
  float acc3 = ldf(bm2, boff + d, f32) + gemv_vec(xs, Wm2_, w0, DD, wf32, red, d);
  {
    float s1 = wave_sum(acc3), s2 = wave_sum(acc3*acc3);
    if (lane == 0){ r1[wid] = s1; r2[wid] = s2; }
  }
  __syncthreads();
  m = 0; qv = 0;
  #pragma unroll
  for (int i = 0; i < 8; ++i){ m += r1[i]; qv += r2[i]; }
  m *= (1.f/DD); var = qv*(1.f/DD) - m*m;
  float y3 = (acc3 - m)*rsqrtf(var + 1e-5f)*ldf(pg, boff+d, f32) + ldf(pb, boff+d, f32);
  float outv = q2 + y3;
  qstate[qoff + d] = outv;
  if (s == 0){
    __syncthreads();
    xs[d] = outv;
    __syncthreads();
    size_t w1 = (size_t)(c+1)*DD*DD;
    float accq = ldf(bq, (size_t)(c+1)*DD + d, f32) + gemv_vec(xs, Wq_, w1, DD, wf32, red, d);
    float t1 = wave_sum(accq) * (1.f/DH);
    float t2 = wave_sum(accq*accq) * (1.f/DH);
    float var2 = t2 - t1*t1;
    qh[(size_t)z*DD + d] = (accq - t1) * rsqrtf(var2 + 1e-5f);
  }
}

__global__ void k_out(const float* __restrict__ qstate, void* __restrict__ dout,
                      const int* __restrict__ flagp){
  int f32 = *flagp;
  int i = blockIdx.x*256 + threadIdx.x;
  if (f32) ((float*)dout)[i] = qstate[i];
  else     ((u16*)dout)[i] = f2bf(qstate[i]);
}

extern "C" void kernel_launch(void* const* d_in, const int* in_sizes, int n_in,
                              void* d_out, int out_size, void* d_ws, size_t ws_size,
                              hipStream_t stream){
  (void)in_sizes; (void)n_in; (void)out_size;
  const void* X   = d_in[0];
  const int* bm    = (const int*)d_in[1];
  const int* ntype = (const int*)d_in[2];
  const void* pmW = d_in[3];  const void* pmb = d_in[4];
  const void* pmg = d_in[5];  const void* pmbn= d_in[6];
  const void* lsig= d_in[7];  const void* rmul= d_in[8];
  const void* Wq  = d_in[9];  const void* bq  = d_in[10];
  const void* Wk  = d_in[11]; const void* bk  = d_in[12];
  const void* Wv  = d_in[13]; const void* bv  = d_in[14];
  const void* Wo  = d_in[15]; const void* bo  = d_in[16];
  const void* ag  = d_in[17]; const void* ab  = d_in[18];
  const void* Wm1 = d_in[19]; const void* bm1 = d_in[20];
  const void* lg  = d_in[21]; const void* lb  = d_in[22];
  const void* Wm2 = d_in[23]; const void* bm2 = d_in[24];
  const void* pg  = d_in[25]; const void* pb  = d_in[26];

  char* ws = (char*)d_ws;
  int*   flagp    = (int*)(ws + 0);
  float* cnt      = (float*)(ws + 256);
  float* bmsum    = (float*)(ws + 512);
  float* colsums  = (float*)(ws + 768);
  float* coltotal = (float*)(ws + 99072);
  float* qstate   = (float*)(ws + 279296);
  int*   cntc     = (int*)(ws + 672512);     // 16 B (pad 256)
  int*   nidx     = (int*)(ws + 672768);     // 64 KB

  size_t off = 738304;
  auto take = [&](size_t bytes)->char*{
    char* p = ws + off; off = (off + bytes + 255) & ~(size_t)255; return p;
  };
  u16* Xbf = (u16*)take((size_t)NB*NN*FF*2);   // 32 MiB bf16 copy of X

  const size_t perT = (size_t)65536           // qh
                    + 16384                   // lpart (NCH=16)
                    + 1048576                 // Opart (NCH=16)
                    + 2*1048576               // WkT, WvT
                    + 2*16777216;             // Kb, Vb
  const size_t wtBytes = (size_t)4*LL*DD*DD*2;      // 25.2 MB
  const size_t pmwbB   = (size_t)FF*DD*2;           // 1 MB
  const size_t wqbB    = (size_t)LL*DD*DD*2;        // 6.3 MB
  size_t base = off;

  int nt = 1;
  if      (ws_size >= base + 6*perT + 65536) nt = 6;
  else if (ws_size >= base + 3*perT + 65536) nt = 3;
  else if (ws_size >= base + 2*perT + 65536) nt = 2;

  float* qh    = (float*)take((size_t)nt*65536);
  float* lpart = (float*)take((size_t)nt*16384);
  float* Opart = (float*)take((size_t)nt*1048576);
  u16*   WkT   = (u16*)take((size_t)nt*1048576);
  u16*   WvT   = (u16*)take((size_t)nt*1048576);
  u16*   Kb    = (u16*)take((size_t)nt*16777216);
  u16*   Vb    = (u16*)take((size_t)nt*16777216);

  int useWt = (ws_size >= off + wtBytes + 65536) ? 1 : 0;
  u16* Wt = useWt ? (u16*)take(wtBytes) : nullptr;
  int useCvt = (ws_size >= off + pmwbB + wqbB + 65536) ? 1 : 0;
  u16* pmWb = useCvt ? (u16*)take(pmwbB) : nullptr;
  u16* Wqb  = useCvt ? (u16*)take(wqbB)  : nullptr;

  const void* WqG = useCvt ? (const void*)Wqb : Wq;
  int wmode = useCvt ? 0 : 1;

  // k_xcv partial buffers carved from Kb (first written by kvgemm, which runs
  // after k_fold/k_mu consumed them -> stream-safe). 14.7 MB <= Kb nt>=1.
  float* Pcol = (float*)Kb;                                  // NXB*NB*TT*FF f32
  float* Ptot = (float*)((char*)Kb + (size_t)NXB*NB*TT*FF*4); // NXB*NB*FF f32

  hipMemsetAsync(ws + 256, 0, 512, stream);    // cnt + bmsum
  k_detect<<<1, 256, 0, stream>>>(X, flagp);
  k_compact<<<NB, 256, 0, stream>>>(bm, nidx, cntc);
  if (useWt)
    k_wbfT<<<dim3(16, 16, 4*LL), dim3(32, 8), 0, stream>>>(Wq, Wo, Wm1, Wm2, Wt, flagp);
  if (useCvt){
    const int n0q = (FF*DD)/4;                      // pmW quads
    const int nblk = (FF*DD + LL*DD*DD)/4/256;
    k_cvt2<<<nblk, 256, 0, stream>>>(pmW, pmWb, n0q, Wq, Wqb, flagp);
  }
  k_xcv<<<dim3(NXB, NB), 256, 0, stream>>>(X, Xbf, bm, ntype, Pcol, Ptot,
                                           cnt, bmsum, flagp);
  k_fold<<<dim3(4, NB*TT), 256, 0, stream>>>(Pcol, Ptot, colsums, coltotal);
  if (useCvt)
    k_mu<<<NB*TT, 512, 0, stream>>>(colsums, coltotal, cnt, bmsum,
        pmWb, pmb, pmg, pmbn, lsig, rmul, qstate, d_out, 0, flagp);
  else
    k_mu<<<NB*TT, 512, 0, stream>>>(colsums, coltotal, cnt, bmsum,
        pmW, pmb, pmg, pmbn, lsig, rmul, qstate, d_out, 1, flagp);

  for (int tlo = 0; tlo < TT; tlo += nt){
    for (int s = 0; s < 2; ++s){
      k_transpose<<<dim3(16, 32, 2*nt), dim3(32, 8), 0, stream>>>(
          Wk, Wv, WkT, WvT, tlo, s, flagp);
      k_kvgemm<<<64*8*nt, 512, 0, stream>>>(
          Xbf, WkT, WvT, bk, bv, Kb, Vb, nidx, cntc, tlo, s, nt, flagp);
      if (s == 0)
        k_qproj<<<nt*32, 512, 0, stream>>>(qstate, WqG, bq, qh, tlo, 0, wmode, flagp);
      k_attnA<<<dim3(NCH, 32, nt), 512, 0, stream>>>(Kb, Vb, qh, cntc, Opart, lpart);
      if (useWt)
        k_tailm<<<32, 512, 0, stream>>>(Opart, lpart, cntc, qstate, qh, Wt,
            bo, ag, ab, bm1, lg, lb, bm2, pg, pb, bq, d_out, tlo, s, nt, flagp);
      else
        k_tail<<<nt*32, 512, 0, stream>>>(Opart, lpart, cntc, qstate, qh,
            Wo, Wm1, Wm2, Wq, bo, ag, ab, bm1, lg, lb, bm2, pg, pb, bq,
            tlo, s, 1, flagp);
    }
  }
  if (!useWt)
    k_out<<<NB*TT*PP*DD/256, 256, 0, stream>>>(qstate, d_out, flagp);
}

// Round 14
// 616.284 us; speedup vs baseline: 1.0979x; 1.0044x over previous
//
#include <hip/hip_runtime.h>
#include <hip/hip_bf16.h>
#include <stdint.h>

#define TT 6
#define PP 8
#define HH 8
#define DD 512
#define FF 1024
#define DH 64
#define NB 4
#define NN 4096
#define LL 12
#define NCH 16
#define CHK 256
#define NXB 128   // k_xcv n-blocks (32 rows each)

typedef __attribute__((ext_vector_type(8))) short short8v;
typedef __attribute__((ext_vector_type(4))) float f32x4;
typedef __attribute__((ext_vector_type(4))) unsigned short u16x4;
typedef __attribute__((ext_vector_type(8))) unsigned short u16x8;
typedef unsigned short u16;

__device__ __forceinline__ float bf2f(u16 u){
  union { unsigned int i; float f; } x; x.i = ((unsigned int)u) << 16; return x.f;
}
__device__ __forceinline__ u16 f2bf(float f){
  union { float f; unsigned int i; } x; x.f = f;
  unsigned int r = x.i + 0x7fffu + ((x.i >> 16) & 1u);
  return (u16)(r >> 16);
}
__device__ __forceinline__ float wave_sum(float x){
  #pragma unroll
  for (int o = 32; o > 0; o >>= 1) x += __shfl_xor(x, o);
  return x;
}
__device__ __forceinline__ float ldf(const void* p, size_t i, int f32){
  float v;
  if (f32) v = ((const float*)p)[i];
  else     v = bf2f(((const u16*)p)[i]);
  return v;
}
// Vectorized block GEMV: y[d] = sum_k xs[k]*W[wbase + k*DD + d], d = tid in [0,512).
__device__ __forceinline__ float gemv_vec(const float* __restrict__ xs,
    const void* __restrict__ W, size_t wbase, int ktot, int wf32,
    float* __restrict__ red, int tid){
  int g = tid & 63, sl = tid >> 6;
  int kpw = ktot >> 3;
  float a[8] = {0,0,0,0,0,0,0,0};
  if (wf32){
    const float* Wp = (const float*)W + wbase + (size_t)(sl*kpw)*DD + g*8;
    #pragma unroll 4
    for (int i = 0; i < kpw; ++i){
      float xv = xs[sl*kpw + i];
      f32x4 lo = *(const f32x4*)(Wp + (size_t)i*DD);
      f32x4 hi = *(const f32x4*)(Wp + (size_t)i*DD + 4);
      a[0]+=xv*lo.x; a[1]+=xv*lo.y; a[2]+=xv*lo.z; a[3]+=xv*lo.w;
      a[4]+=xv*hi.x; a[5]+=xv*hi.y; a[6]+=xv*hi.z; a[7]+=xv*hi.w;
    }
  } else {
    const u16* Wp = (const u16*)W + wbase + (size_t)(sl*kpw)*DD + g*8;
    #pragma unroll 4
    for (int i = 0; i < kpw; ++i){
      float xv = xs[sl*kpw + i];
      u16x8 w8 = *(const u16x8*)(Wp + (size_t)i*DD);
      #pragma unroll
      for (int j = 0; j < 8; ++j) a[j] += xv * bf2f(w8[j]);
    }
  }
  #pragma unroll
  for (int j = 0; j < 8; ++j) red[sl*512 + g*8 + j] = a[j];
  __syncthreads();
  float y = 0;
  #pragma unroll
  for (int s2 = 0; s2 < 8; ++s2) y += red[s2*512 + tid];
  return y;
}
// async global->LDS, 16B per lane. Global src IS per-lane (gather/swizzle OK);
// LDS dest must be wave-uniform base + lane*16 (linear).
__device__ __forceinline__ void glds16(const void* g, void* l){
#if __has_builtin(__builtin_amdgcn_global_load_lds)
  __builtin_amdgcn_global_load_lds(
      (const __attribute__((address_space(1))) void*)g,
      (__attribute__((address_space(3))) void*)l, 16, 0, 0);
#else
  *(u16x8*)l = *(const u16x8*)g;
#endif
}

// flag=1 -> inputs are float32 ; flag=0 -> inputs are bf16
__global__ void k_detect(const void* __restrict__ X, int* __restrict__ flag){
  int tid = threadIdx.x;
  const u16* u = (const u16*)X;
  int bad = 0;
  for (int i = tid; i < 8192; i += 256){
    int ex = (u[i] >> 7) & 0xFF;
    if (ex >= 0x90) bad = 1;
  }
  __shared__ int s;
  if (tid == 0) s = 0;
  __syncthreads();
  if (bad) s = 1;
  __syncthreads();
  if (tid == 0) *flag = s;
}

// fused dual f32->bf16 (or bf16 copy) converter: array0 quads [0,n0q),
// array1 quads [n0q, ...). One dispatch for pmW + Wq.
__global__ void k_cvt2(const void* __restrict__ s0, u16* __restrict__ d0, int n0q,
                       const void* __restrict__ s1, u16* __restrict__ d1,
                       const int* __restrict__ flagp){
  int f32 = *flagp;
  size_t q = (size_t)blockIdx.x*256 + threadIdx.x;
  const void* s; u16* d; size_t i;
  if (q < (size_t)n0q){ s = s0; d = d0; i = q*4; }
  else                { s = s1; d = d1; i = (q - n0q)*4; }
  if (f32){
    f32x4 v = *(const f32x4*)((const float*)s + i);
    u16x4 o; o.x=f2bf(v.x); o.y=f2bf(v.y); o.z=f2bf(v.z); o.w=f2bf(v.w);
    *(u16x4*)(d+i) = o;
  } else {
    *(u16x4*)(d+i) = *(const u16x4*)((const u16*)s + i);
  }
}

// FUSED X pass: X -> bf16 copy + per-type column PARTIALS (no f32 atomics).
// Partials go to Pcol/Ptot (carved from Kb; kvgemm writes Kb only after k_mu
// consumed them -> stream-safe). cnt/bmsum keep tiny integer atomics (exact).
__global__ void k_xcv(const void* __restrict__ X, u16* __restrict__ Xb,
                      const int* __restrict__ bm, const int* __restrict__ ntype,
                      float* __restrict__ Pcol, float* __restrict__ Ptot,
                      float* __restrict__ cnt, float* __restrict__ bmsum,
                      const int* __restrict__ flagp){
  int f32 = *flagp;
  int b = blockIdx.y, blk = blockIdx.x;
  int n0 = blk * 32;
  int tid = threadIdx.x;
  int f0 = tid * 4;
  __shared__ int sflag[32];
  __shared__ float scnt[TT+1];
  if (tid < 32) sflag[tid] = 0;
  if (tid < TT+1) scnt[tid] = 0.f;
  __syncthreads();
  float acc[TT][4] = {};
  float tot[4] = {0,0,0,0};
  for (int i = 0; i < 32; ++i){
    int n = n0 + i;
    size_t idx = (size_t)(b*NN+n)*FF + f0;
    u16x4 xb;
    bool a;
    if (f32){
      f32x4 v = *(const f32x4*)((const float*)X + idx);
      xb.x=f2bf(v.x); xb.y=f2bf(v.y); xb.z=f2bf(v.z); xb.w=f2bf(v.w);
      a = (v.x!=0.f)||(v.y!=0.f)||(v.z!=0.f)||(v.w!=0.f);
    } else {
      xb = *(const u16x4*)((const u16*)X + idx);
      a = (bf2f(xb.x)!=0.f)||(bf2f(xb.y)!=0.f)||(bf2f(xb.z)!=0.f)||(bf2f(xb.w)!=0.f);
    }
    *(u16x4*)(Xb+idx) = xb;
    if (a) sflag[i] = 1;
    float vbm = (bm[b*NN+n] != 0) ? 1.f : 0.f;
    int ty = ntype[b*NN+n];
    #pragma unroll
    for (int j = 0; j < 4; ++j){
      float xv = bf2f(xb[j]);
      tot[j] += xv;
      float xvv = xv * vbm;
      #pragma unroll
      for (int t = 0; t < TT; ++t) acc[t][j] += (ty==t) ? xvv : 0.f;
    }
  }
  __syncthreads();
  if (tid < 32){
    int n = n0 + tid;
    if (bm[b*NN+n] != 0){
      if (sflag[tid]) atomicAdd(&scnt[ntype[b*NN+n]], 1.f);
      atomicAdd(&scnt[TT], 1.f);
    }
  }
  size_t pbase = (size_t)blk*NB + b;
  #pragma unroll
  for (int t = 0; t < TT; ++t){
    f32x4 v = {acc[t][0], acc[t][1], acc[t][2], acc[t][3]};
    *(f32x4*)&Pcol[(pbase*TT + t)*FF + f0] = v;
  }
  {
    f32x4 v = {tot[0], tot[1], tot[2], tot[3]};
    *(f32x4*)&Ptot[pbase*FF + f0] = v;
  }
  __syncthreads();
  if (tid < TT) atomicAdd(&cnt[b*TT + tid], scnt[tid]);
  if (tid == TT) atomicAdd(&bmsum[b], scnt[TT]);
}

// fold the NXB partials -> colsums/coltotal (parallel: 96 blocks vs the old
// in-k_mu 24-block serial fold). Same ascending blk add order -> bitwise same.
__global__ void k_fold(const float* __restrict__ Pcol, const float* __restrict__ Ptot,
                       float* __restrict__ colsums, float* __restrict__ coltotal){
  int fb = blockIdx.x;            // 0..3
  int bt = blockIdx.y;            // 0..NB*TT-1
  int b = bt / TT, t = bt % TT;
  int f = fb*256 + threadIdx.x;
  float S = 0.f;
  #pragma unroll 4
  for (int blk = 0; blk < NXB; ++blk)
    S += Pcol[(((size_t)blk*NB + b)*TT + t)*FF + f];
  colsums[(size_t)bt*FF + f] = S;
  if (t == 0){
    float T = 0.f;
    #pragma unroll 4
    for (int blk = 0; blk < NXB; ++blk)
      T += Ptot[((size_t)blk*NB + b)*FF + f];
    coltotal[b*FF + f] = T;
  }
}

// per-batch stable compaction of valid (bm!=0) key indices
__global__ void k_compact(const int* __restrict__ bm, int* __restrict__ nidx,
                          int* __restrict__ cntc){
  int b = blockIdx.x, tid = threadIdx.x;   // 256 threads, 16 entries each
  __shared__ int csum[256];
  __shared__ int pref[257];
  int base = b*NN + tid*16;
  int f[16]; int loc = 0;
  #pragma unroll
  for (int i = 0; i < 16; ++i){ f[i] = (bm[base+i] != 0); loc += f[i]; }
  csum[tid] = loc;
  __syncthreads();
  if (tid == 0){
    pref[0] = 0;
    for (int j = 0; j < 256; ++j) pref[j+1] = pref[j] + csum[j];
  }
  __syncthreads();
  int off = b*NN + pref[tid];
  #pragma unroll
  for (int i = 0; i < 16; ++i){ if (f[i]) nidx[off++] = tid*16 + i; }
  if (tid == 0) cntc[b] = pref[256];
}

// FUSED proto_mu + mu (folded inputs): writes the proto_mu region of d_out,
// then the pmW GEMV + LN + gelu + expand.
__global__ void __launch_bounds__(512) k_mu(const float* __restrict__ colsums,
   const float* __restrict__ coltotal, const float* __restrict__ cnt,
   const float* __restrict__ bmsum,
   const void* __restrict__ pmWx, const void* __restrict__ pmb,
   const void* __restrict__ pmg, const void* __restrict__ pmbn,
   const void* __restrict__ lsig, const void* __restrict__ rmul,
   float* __restrict__ qstate, void* __restrict__ dout, int wmode,
   const int* __restrict__ flagp){
  int f32 = *flagp;
  int wf32 = wmode ? f32 : 0;
  const size_t OFFP = (size_t)NB*TT*PP*DD;
  int bt = blockIdx.x; int b = bt/TT, t = bt%TT;
  int d = threadIdx.x;
  __shared__ float xs[FF];
  __shared__ float red[4096];
  __shared__ float r1[8], r2[8];
  float cv = cnt[bt];
  float inv = 1.f / fmaxf(cv, 1.f);
  float fbinv = 1.f / bmsum[b];
  #pragma unroll
  for (int h = 0; h < 2; ++h){
    int f = d + h*512;
    float pm = (cv > 0.f) ? colsums[(size_t)bt*FF + f] * inv
                          : coltotal[b*FF + f] * fbinv;
    xs[f] = pm;
    if (f32) ((float*)dout)[OFFP + (size_t)bt*FF + f] = pm;
    else     ((u16*)dout)[OFFP + (size_t)bt*FF + f] = f2bf(pm);
  }
  __syncthreads();
  float acc = ldf(pmb, d, f32) + gemv_vec(xs, pmWx, 0, FF, wf32, red, d);
  int lane = d & 63, wid = d >> 6;
  float s1 = wave_sum(acc), s2 = wave_sum(acc*acc);
  if (lane==0){ r1[wid]=s1; r2[wid]=s2; }
  __syncthreads();
  float m=0, qq=0;
  #pragma unroll
  for (int i=0;i<8;++i){ m+=r1[i]; qq+=r2[i]; }
  m *= (1.f/DD); float var = qq*(1.f/DD) - m*m;
  float y = (acc - m) * rsqrtf(var + 1e-5f) * ldf(pmg, d, f32) + ldf(pmbn, d, f32);
  float mu = 0.5f * y * (1.f + erff(y * 0.70710678118654752f));
  #pragma unroll
  for (int p = 0; p < PP; ++p){
    float rv = ldf(rmul, (size_t)(t*PP+p)*DD + d, f32);
    float ls = ldf(lsig, (size_t)t*DD + d, f32);
    qstate[(((size_t)(b*TT+t))*PP + p)*DD + d] = mu + expf(ls) * rv;
  }
}

// batched transpose: z = ti*2 + kv ; layer c = 2*(tlo+ti)+s
__global__ void k_transpose(const void* __restrict__ Wk, const void* __restrict__ Wv,
                            u16* __restrict__ TK, u16* __restrict__ TV,
                            int tlo, int s, const int* __restrict__ flagp){
  int f32 = *flagp;
  int ti = blockIdx.z >> 1, kv = blockIdx.z & 1;
  int c = 2*(tlo+ti)+s;
  size_t eoff = (size_t)c*FF*DD;
  const void* W = kv ? Wv : Wk;
  u16* T = (kv ? TV : TK) + (size_t)ti*FF*DD;
  __shared__ u16 tile[32][33];
  int n0 = blockIdx.x * 32, k0 = blockIdx.y * 32;
  int tx = threadIdx.x, ty = threadIdx.y;
  #pragma unroll
  for (int i = 0; i < 4; ++i){
    size_t idx = eoff + (size_t)(k0 + ty + i*8)*DD + n0 + tx;
    u16 v;
    if (f32) v = f2bf(((const float*)W)[idx]);
    else     v = ((const u16*)W)[idx];
    tile[ty + i*8][tx] = v;
  }
  __syncthreads();
  #pragma unroll
  for (int i = 0; i < 4; ++i)
    T[(size_t)(n0 + ty + i*8)*FF + k0 + tx] = tile[tx][ty + i*8];
}

// ---- K/V GEMM: BM=256 x BN=128, BK=32, 512 thr / 8 waves, 3-buffer LDS ring
// (72 KB -> 2 blocks/CU). One barrier + counted vmcnt(3) per K-tile.
// K/V stored HEAD-MAJOR [b][h][n][64] so k_attnA reads contiguous 128B rows.
// Measured local optimum (124us, VGPR 64, 2 blocks/CU) -- r12 epilogue
// experiment and r5/r1 tile experiments all regressed. DO NOT TOUCH.
__global__ void __launch_bounds__(512) k_kvgemm(const u16* __restrict__ Xb,
    const u16* __restrict__ TK, const u16* __restrict__ TV,
    const void* __restrict__ bk, const void* __restrict__ bv,
    u16* __restrict__ Kb, u16* __restrict__ Vb,
    const int* __restrict__ nidx, const int* __restrict__ cntc,
    int tlo, int s, int nt, const int* __restrict__ flagp){
  int f32 = *flagp;
  int orig = blockIdx.x;
  int x = orig & 7, r = orig >> 3;
  int bx = r / nt, pr = r - bx*nt;
  int pairg = x*nt + pr;                 // [0, 8*nt)
  int by = pairg & 3; int kvti = pairg >> 2; int kv = kvti & 1; int ti = kvti >> 1;
  int b = bx >> 4, jt = bx & 15;
  int cnt = cntc[b];
  if (jt*256 >= cnt) return;             // uniform early exit
  int c = 2*(tlo+ti)+s;
  size_t boff = (size_t)c*DD;
  const u16* WT = (kv ? TV : TK) + (size_t)ti*FF*DD;
  const void* bias = kv ? bv : bk;
  u16* out = (kv ? Vb : Kb) + (size_t)ti*((size_t)NB*NN*DD);
  int n0 = by*128;
  __shared__ __align__(16) char LDS[3*24576];
  int tid = threadIdx.x, wid = tid >> 6, lane = tid & 63;
  int wr = wid >> 1, wcn = wid & 1;
  const u16* gp0; const u16* gp1; const u16* gp2;
  int lo0, lo1, lo2;
  {
    const u16* gps[3]; int los[3];
    #pragma unroll
    for (int i = 0; i < 3; ++i){
      int e = tid + i*512;
      if (e < 1024){                      // A segs
        int row = e>>2, sp = e&3;
        int ssrc = sp ^ (((row>>3)&1)<<1);
        int cl = jt*256 + row; if (cl >= cnt) cl = cnt-1;
        int grow = nidx[b*NN + cl];
        gps[i] = Xb + ((size_t)b*NN + grow)*FF + ssrc*8;
        los[i] = e*16;
      } else {                            // B segs
        int e2 = e - 1024;
        int row = e2>>2, sp = e2&3;
        int ssrc = sp ^ (((row>>3)&1)<<1);
        gps[i] = WT + (size_t)(n0 + row)*FF + ssrc*8;
        los[i] = 16384 + e2*16;
      }
    }
    gp0=gps[0]; gp1=gps[1]; gp2=gps[2];
    lo0=los[0]; lo1=los[1]; lo2=los[2];
  }
#define STAGE(T) { char* bb_ = LDS + ((T)%3)*24576; \
  glds16(gp0 + (T)*32, bb_ + lo0); glds16(gp1 + (T)*32, bb_ + lo1); \
  glds16(gp2 + (T)*32, bb_ + lo2); }
  int ke = (lane>>4) ^ (((lane>>3)&1)<<1);
  int arow[4], brow[4];
  #pragma unroll
  for (int mi = 0; mi < 4; ++mi)
    arow[mi] = (wr*64 + mi*16 + (lane&15))*64 + ke*16;
  #pragma unroll
  for (int ni = 0; ni < 4; ++ni)
    brow[ni] = 16384 + (wcn*64 + ni*16 + (lane&15))*64 + ke*16;
  f32x4 acc[4][4] = {};
  STAGE(0);
  STAGE(1);
  asm volatile("s_waitcnt vmcnt(3)" ::: "memory");
  __builtin_amdgcn_sched_barrier(0);
  __builtin_amdgcn_s_barrier();
  __builtin_amdgcn_sched_barrier(0);
  #pragma unroll
  for (int t = 0; t < 32; ++t){
    const char* Bbuf = LDS + (t%3)*24576;
    short8v af[4], bf[4];
    #pragma unroll
    for (int mi = 0; mi < 4; ++mi)
      af[mi] = *(const short8v*)(Bbuf + arow[mi]);
    #pragma unroll
    for (int ni = 0; ni < 4; ++ni)
      bf[ni] = *(const short8v*)(Bbuf + brow[ni]);
    if (t + 2 <= 31) STAGE(t+2);           // buf (t+2)%3: disjoint from t, t+1
    __builtin_amdgcn_s_setprio(1);
    #pragma unroll
    for (int mi = 0; mi < 4; ++mi)
      #pragma unroll
      for (int ni = 0; ni < 4; ++ni)
        acc[mi][ni] = __builtin_amdgcn_mfma_f32_16x16x32_bf16(af[mi], bf[ni], acc[mi][ni], 0, 0, 0);
    __builtin_amdgcn_s_setprio(0);
    if (t < 30)       asm volatile("s_waitcnt vmcnt(3)" ::: "memory");
    else if (t == 30) asm volatile("s_waitcnt vmcnt(0)" ::: "memory");
    __builtin_amdgcn_sched_barrier(0);
    if (t < 31){
      __builtin_amdgcn_s_barrier();
      __builtin_amdgcn_sched_barrier(0);
    }
  }
#undef STAGE
  #pragma unroll
  for (int mi = 0; mi < 4; ++mi){
    #pragma unroll
    for (int ni = 0; ni < 4; ++ni){
      int col = n0 + wcn*64 + ni*16 + (lane & 15);
      int h = col >> 6, dh = col & 63;          // head-major store
      float bvf = ldf(bias, boff + col, f32);
      #pragma unroll
      for (int r2 = 0; r2 < 4; ++r2){
        int row = jt*256 + wr*64 + mi*16 + (lane>>4)*4 + r2;   // compact slot
        out[(((size_t)(b*HH + h))*NN + row)*DH + dh] = f2bf(acc[mi][ni][r2] + bvf);
      }
    }
  }
}

// standalone q projection + per-head LN (first stage of each tlo batch)
__global__ void __launch_bounds__(512) k_qproj(const float* __restrict__ qstate,
      const void* __restrict__ Wq, const void* __restrict__ bq,
      float* __restrict__ qh, int tlo, int s, int wmode,
      const int* __restrict__ flagp){
  int f32 = *flagp;
  int wf32 = wmode ? f32 : 0;
  int z = blockIdx.x; int ti = z >> 5, rr = z & 31;
  int b = rr >> 3, p = rr & 7;
  int t = tlo + ti, c = 2*t + s;
  size_t woff = (size_t)c*DD*DD, boff = (size_t)c*DD;
  int d = threadIdx.x;
  __shared__ float xs[DD];
  __shared__ float red[4096];
  const float* xrow = qstate + (((size_t)(b*TT+t))*PP + p)*DD;
  xs[d] = xrow[d];
  __syncthreads();
  float acc = ldf(bq, boff + d, f32) + gemv_vec(xs, Wq, woff, DD, wf32, red, d);
  float s1 = wave_sum(acc) * (1.f/DH);
  float s2 = wave_sum(acc*acc) * (1.f/DH);
  float var = s2 - s1*s1;
  qh[(size_t)z*DD + d] = (acc - s1) * rsqrtf(var + 1e-5f);
}

// attention partials over COMPACTED keys. K/V are HEAD-MAJOR [b][h][n][64].
// K not LDS-staged (single use, coalesced); V staged (64x reuse). LDS 44KB.
__global__ void __launch_bounds__(512) k_attnA(const u16* __restrict__ Kb,
     const u16* __restrict__ Vb, const float* __restrict__ qh,
     const int* __restrict__ cntc, float* __restrict__ Opart, float* __restrict__ lpart){
  int ic = blockIdx.x, bh = blockIdx.y, ti = blockIdx.z;
  int b = bh >> 3, h = bh & 7;
  int cnt = cntc[b];
  if (ic*CHK >= cnt) return;              // uniform early exit (pre-barrier)
  int tid = threadIdx.x, p8 = tid >> 6, ln = tid & 63;
  int r8 = ln >> 3, g = ln & 7;
  __shared__ __align__(16) char KV[32768];   // Vs only [256r][128B]
  __shared__ float qs[PP*DH];
  __shared__ float qsum[PP];
  __shared__ float e_lds[CHK*9];
  int rem = cnt - ic*CHK;                 // >=1 here
  float qv = qh[((size_t)(ti*32 + b*PP + p8))*DD + h*DH + ln];
  size_t tioff = (size_t)ti*((size_t)NB*NN*DD);
  const u16* Kbase = Kb + tioff + ((size_t)(b*HH + h)*NN + (size_t)ic*CHK)*DH;
  const u16* Vbase = Vb + tioff + ((size_t)(b*HH + h)*NN + (size_t)ic*CHK)*DH;
  #pragma unroll
  for (int i = 0; i < 4; ++i){
    int e = tid + i*512;
    int row = e >> 3, sp = e & 7;
    int ss = sp ^ (row & 7);
    int rr = row < rem ? row : rem-1;
    glds16(Vbase + (size_t)rr*DH + ss*8, (char*)KV + e*16);
  }
  qs[p8*DH + ln] = qv;
  {
    float sQ = wave_sum(qv);
    if (ln == 0) qsum[p8] = sQ;
  }
  asm volatile("s_waitcnt lgkmcnt(0)" ::: "memory");
  __builtin_amdgcn_sched_barrier(0);
  __builtin_amdgcn_s_barrier();
  __builtin_amdgcn_sched_barrier(0);
  #pragma unroll
  for (int it = 0; it < CHK/64; ++it){
    int nl = it*64 + p8*8 + r8;
    int rr8 = nl < rem ? nl : rem-1;
    u16x8 kv8 = *(const u16x8*)(Kbase + (size_t)rr8*DH + g*8);   // direct, coalesced
    float kf[8];
    #pragma unroll
    for (int e = 0; e < 8; ++e) kf[e] = bf2f(kv8[e]);
    float sm = 0, sq = 0;
    #pragma unroll
    for (int e = 0; e < 8; ++e){ sm += kf[e]; sq += kf[e]*kf[e]; }
    #pragma unroll
    for (int o = 1; o < 8; o <<= 1){
      sm += __shfl_xor(sm, o);
      sq += __shfl_xor(sq, o);
    }
    sm *= (1.f/DH); sq = sq*(1.f/DH) - sm*sm;
    float inv = rsqrtf(sq + 1e-5f);
    float ap[8];
    #pragma unroll
    for (int p = 0; p < 8; ++p){
      f32x4 qa = *(const f32x4*)&qs[p*DH + g*8];
      f32x4 qb = *(const f32x4*)&qs[p*DH + g*8 + 4];
      ap[p] = kf[0]*qa.x + kf[1]*qa.y + kf[2]*qa.z + kf[3]*qa.w
            + kf[4]*qb.x + kf[5]*qb.y + kf[6]*qb.z + kf[7]*qb.w;
    }
    #pragma unroll
    for (int o = 1; o < 8; o <<= 1){
      #pragma unroll
      for (int p = 0; p < 8; ++p) ap[p] += __shfl_xor(ap[p], o);
    }
    float dg = (g==0)?ap[0]:(g==1)?ap[1]:(g==2)?ap[2]:(g==3)?ap[3]
             : (g==4)?ap[4]:(g==5)?ap[5]:(g==6)?ap[6]:ap[7];
    float sv = (dg - sm*qsum[g]) * inv * 0.125f;
    e_lds[nl*9 + g] = (nl < rem) ? __expf(sv) : 0.f;
  }
  __syncthreads();   // drains vmcnt(0): V staged; e_lds visible cross-wave
  {
    float lp = 0;
    #pragma unroll
    for (int j = 0; j < CHK/64; ++j) lp += e_lds[(ln + j*64)*9 + p8];
    lp = wave_sum(lp);
    if (ln == 0) lpart[((size_t)(ti*32+bh)*NCH + ic)*PP + p8] = lp;
  }
  {
    float a0=0,a1=0,a2=0,a3=0,a4=0,a5=0,a6=0,a7=0;
    int vseg = (r8 ^ g) * 16;
    #pragma unroll 4
    for (int m = 0; m < CHK/8; ++m){
      float e = e_lds[(g + m*8)*9 + p8];
      u16x8 vv = *(const u16x8*)((const char*)KV + (g + m*8)*128 + vseg);
      a0 += e*bf2f(vv[0]); a1 += e*bf2f(vv[1]);
      a2 += e*bf2f(vv[2]); a3 += e*bf2f(vv[3]);
      a4 += e*bf2f(vv[4]); a5 += e*bf2f(vv[5]);
      a6 += e*bf2f(vv[6]); a7 += e*bf2f(vv[7]);
    }
    #pragma unroll
    for (int o = 1; o < 8; o <<= 1){
      a0 += __shfl_xor(a0, o); a1 += __shfl_xor(a1, o);
      a2 += __shfl_xor(a2, o); a3 += __shfl_xor(a3, o);
      a4 += __shfl_xor(a4, o); a5 += __shfl_xor(a5, o);
      a6 += __shfl_xor(a6, o); a7 += __shfl_xor(a7, o);
    }
    if (g == 0){
      float* op = Opart + ((size_t)(ti*32+bh)*NCH + ic)*512 + p8*64 + r8*8;
      f32x4 lo = {a0,a1,a2,a3}, hi = {a4,a5,a6,a7};
      *(f32x4*)op = lo;
      *((f32x4*)op + 1) = hi;
    }
  }
}

// GEMV tail (primary path at 256MiB ws). r14: s==1 writes d_out directly
// (replaces k_out; each t's final qstate is produced in its own s==1 pass);
// odd-layer Wq GEMV reads bf16 copy (same precedent as qproj since r6).
__global__ void __launch_bounds__(512) k_tail(
    const float* __restrict__ Opart, const float* __restrict__ lpart,
    const int* __restrict__ cntc,
    float* __restrict__ qstate, float* __restrict__ qh,
    const void* __restrict__ Wo_, const void* __restrict__ Wm1_,
    const void* __restrict__ Wm2_, const void* __restrict__ Wq_,
    const void* __restrict__ bo, const void* __restrict__ ag, const void* __restrict__ ab,
    const void* __restrict__ bm1, const void* __restrict__ lg, const void* __restrict__ lb,
    const void* __restrict__ bm2, const void* __restrict__ pg, const void* __restrict__ pb,
    const void* __restrict__ bq, void* __restrict__ dout,
    int tlo, int s, int wmode, int wqmode, const int* __restrict__ flagp){
  int f32 = *flagp;
  int wf32 = wmode ? f32 : 0;
  int z = blockIdx.x; int ti = z >> 5, rr = z & 31;
  int b = rr >> 3, p = rr & 7;
  int t = tlo + ti, c = 2*t + s;
  int d = threadIdx.x;
  int h = d >> 6, dd = d & 63;
  int lane = d & 63, wid = d >> 6;
  size_t qoff = (((size_t)(b*TT+t))*PP + p)*DD;
  size_t boff = (size_t)c*DD;
  size_t w0 = (size_t)c*DD*DD;
  __shared__ float xs[DD];
  __shared__ float red[4096];
  __shared__ float r1[8], r2[8];
  int nch = (cntc[b] + CHK - 1) / CHK;
  float o = 0, l = 0;
  for (int ic = 0; ic < nch; ++ic){
    o += Opart[((size_t)(ti*32 + b*8 + h)*NCH + ic)*512 + p*64 + dd];
    l += lpart[((size_t)(ti*32 + b*8 + h)*NCH + ic)*PP + p];
  }
  float upd = o / l;
  xs[d] = upd;
  __syncthreads();
  float acc = ldf(bo, boff + d, f32) + gemv_vec(xs, Wo_, w0, DD, wf32, red, d);
  {
    float s1 = wave_sum(acc), s2 = wave_sum(acc*acc);
    if (lane == 0){ r1[wid] = s1; r2[wid] = s2; }
  }
  __syncthreads();
  float m = 0, qv = 0;
  #pragma unroll
  for (int i = 0; i < 8; ++i){ m += r1[i]; qv += r2[i]; }
  m *= (1.f/DD); float var = qv*(1.f/DD) - m*m;
  float y = (acc - m)*rsqrtf(var + 1e-5f)*ldf(ag, boff+d, f32) + ldf(ab, boff+d, f32);
  float q2 = qstate[qoff + d] + y;
  __syncthreads();
  xs[d] = q2;
  __syncthreads();
  float acc2 = ldf(bm1, boff + d, f32) + gemv_vec(xs, Wm1_, w0, DD, wf32, red, d);
  {
    float s1 = wave_sum(acc2), s2 = wave_sum(acc2*acc2);
    if (lane == 0){ r1[wid] = s1; r2[wid] = s2; }
  }
  __syncthreads();
  m = 0; qv = 0;
  #pragma unroll
  for (int i = 0; i < 8; ++i){ m += r1[i]; qv += r2[i]; }
  m *= (1.f/DD); var = qv*(1.f/DD) - m*m;
  float y2 = (acc2 - m)*rsqrtf(var + 1e-5f)*ldf(lg, boff+d, f32) + ldf(lb, boff+d, f32);
  y2 = 0.5f*y2*(1.f + erff(y2*0.70710678118654752f));
  __syncthreads();
  xs[d] = y2;
  __syncthreads();
  float acc3 = ldf(bm2, boff + d, f32) + gemv_vec(xs, Wm2_, w0, DD, wf32, red, d);
  {
    float s1 = wave_sum(acc3), s2 = wave_sum(acc3*acc3);
    if (lane == 0){ r1[wid] = s1; r2[wid] = s2; }
  }
  __syncthreads();
  m = 0; qv = 0;
  #pragma unroll
  for (int i = 0; i < 8; ++i){ m += r1[i]; qv += r2[i]; }
  m *= (1.f/DD); var = qv*(1.f/DD) - m*m;
  float y3 = (acc3 - m)*rsqrtf(var + 1e-5f)*ldf(pg, boff+d, f32) + ldf(pb, boff+d, f32);
  float outv = q2 + y3;
  qstate[qoff + d] = outv;
  if (s == 1){
    if (f32) ((float*)dout)[qoff + d] = outv;
    else     ((u16*)dout)[qoff + d] = f2bf(outv);
  }
  if (s == 0){
    __syncthreads();
    xs[d] = outv;
    __syncthreads();
    size_t w1 = (size_t)(c+1)*DD*DD;
    int wq32 = wqmode ? f32 : 0;
    float accq = ldf(bq, (size_t)(c+1)*DD + d, f32) + gemv_vec(xs, Wq_, w1, DD, wq32, red, d);
    float t1 = wave_sum(accq) * (1.f/DH);
    float t2 = wave_sum(accq*accq) * (1.f/DH);
    float var2 = t2 - t1*t1;
    qh[(size_t)z*DD + d] = (accq - t1) * rsqrtf(var2 + 1e-5f);
  }
}

extern "C" void kernel_launch(void* const* d_in, const int* in_sizes, int n_in,
                              void* d_out, int out_size, void* d_ws, size_t ws_size,
                              hipStream_t stream){
  (void)in_sizes; (void)n_in; (void)out_size;
  const void* X   = d_in[0];
  const int* bm    = (const int*)d_in[1];
  const int* ntype = (const int*)d_in[2];
  const void* pmW = d_in[3];  const void* pmb = d_in[4];
  const void* pmg = d_in[5];  const void* pmbn= d_in[6];
  const void* lsig= d_in[7];  const void* rmul= d_in[8];
  const void* Wq  = d_in[9];  const void* bq  = d_in[10];
  const void* Wk  = d_in[11]; const void* bk  = d_in[12];
  const void* Wv  = d_in[13]; const void* bv  = d_in[14];
  const void* Wo  = d_in[15]; const void* bo  = d_in[16];
  const void* ag  = d_in[17]; const void* ab  = d_in[18];
  const void* Wm1 = d_in[19]; const void* bm1 = d_in[20];
  const void* lg  = d_in[21]; const void* lb  = d_in[22];
  const void* Wm2 = d_in[23]; const void* bm2 = d_in[24];
  const void* pg  = d_in[25]; const void* pb  = d_in[26];

  char* ws = (char*)d_ws;
  int*   flagp    = (int*)(ws + 0);
  float* cnt      = (float*)(ws + 256);
  float* bmsum    = (float*)(ws + 512);
  float* colsums  = (float*)(ws + 768);
  float* coltotal = (float*)(ws + 99072);
  float* qstate   = (float*)(ws + 279296);
  int*   cntc     = (int*)(ws + 672512);     // 16 B (pad 256)
  int*   nidx     = (int*)(ws + 672768);     // 64 KB

  size_t off = 738304;
  auto take = [&](size_t bytes)->char*{
    char* p = ws + off; off = (off + bytes + 255) & ~(size_t)255; return p;
  };
  u16* Xbf = (u16*)take((size_t)NB*NN*FF*2);   // 32 MiB bf16 copy of X

  const size_t perT = (size_t)65536           // qh
                    + 16384                   // lpart (NCH=16)
                    + 1048576                 // Opart (NCH=16)
                    + 2*1048576               // WkT, WvT
                    + 2*16777216;             // Kb, Vb
  const size_t pmwbB   = (size_t)FF*DD*2;           // 1 MB
  const size_t wqbB    = (size_t)LL*DD*DD*2;        // 6.3 MB
  size_t base = off;

  int nt = 1;
  if      (ws_size >= base + 6*perT + 65536) nt = 6;
  else if (ws_size >= base + 3*perT + 65536) nt = 3;
  else if (ws_size >= base + 2*perT + 65536) nt = 2;

  float* qh    = (float*)take((size_t)nt*65536);
  float* lpart = (float*)take((size_t)nt*16384);
  float* Opart = (float*)take((size_t)nt*1048576);
  u16*   WkT   = (u16*)take((size_t)nt*1048576);
  u16*   WvT   = (u16*)take((size_t)nt*1048576);
  u16*   Kb    = (u16*)take((size_t)nt*16777216);
  u16*   Vb    = (u16*)take((size_t)nt*16777216);

  int useCvt = (ws_size >= off + pmwbB + wqbB + 65536) ? 1 : 0;
  u16* pmWb = useCvt ? (u16*)take(pmwbB) : nullptr;
  u16* Wqb  = useCvt ? (u16*)take(wqbB)  : nullptr;

  const void* WqG = useCvt ? (const void*)Wqb : Wq;
  int wmode = useCvt ? 0 : 1;

  // k_xcv partial buffers carved from Kb (first written by kvgemm, which runs
  // after k_fold/k_mu consumed them -> stream-safe). 14.7 MB <= Kb nt>=1.
  float* Pcol = (float*)Kb;                                  // NXB*NB*TT*FF f32
  float* Ptot = (float*)((char*)Kb + (size_t)NXB*NB*TT*FF*4); // NXB*NB*FF f32

  hipMemsetAsync(ws + 256, 0, 512, stream);    // cnt + bmsum
  k_detect<<<1, 256, 0, stream>>>(X, flagp);
  k_compact<<<NB, 256, 0, stream>>>(bm, nidx, cntc);
  if (useCvt){
    const int n0q = (FF*DD)/4;                      // pmW quads
    const int nblk = (FF*DD + LL*DD*DD)/4/256;
    k_cvt2<<<nblk, 256, 0, stream>>>(pmW, pmWb, n0q, Wq, Wqb, flagp);
  }
  k_xcv<<<dim3(NXB, NB), 256, 0, stream>>>(X, Xbf, bm, ntype, Pcol, Ptot,
                                           cnt, bmsum, flagp);
  k_fold<<<dim3(4, NB*TT), 256, 0, stream>>>(Pcol, Ptot, colsums, coltotal);
  if (useCvt)
    k_mu<<<NB*TT, 512, 0, stream>>>(colsums, coltotal, cnt, bmsum,
        pmWb, pmb, pmg, pmbn, lsig, rmul, qstate, d_out, 0, flagp);
  else
    k_mu<<<NB*TT, 512, 0, stream>>>(colsums, coltotal, cnt, bmsum,
        pmW, pmb, pmg, pmbn, lsig, rmul, qstate, d_out, 1, flagp);

  for (int tlo = 0; tlo < TT; tlo += nt){
    for (int s = 0; s < 2; ++s){
      k_transpose<<<dim3(16, 32, 2*nt), dim3(32, 8), 0, stream>>>(
          Wk, Wv, WkT, WvT, tlo, s, flagp);
      k_kvgemm<<<64*8*nt, 512, 0, stream>>>(
          Xbf, WkT, WvT, bk, bv, Kb, Vb, nidx, cntc, tlo, s, nt, flagp);
      if (s == 0)
        k_qproj<<<nt*32, 512, 0, stream>>>(qstate, WqG, bq, qh, tlo, 0, wmode, flagp);
      k_attnA<<<dim3(NCH, 32, nt), 512, 0, stream>>>(Kb, Vb, qh, cntc, Opart, lpart);
      k_tail<<<nt*32, 512, 0, stream>>>(Opart, lpart, cntc, qstate, qh,
          Wo, Wm1, Wm2, WqG, bo, ag, ab, bm1, lg, lb, bm2, pg, pb, bq, d_out,
          tlo, s, 1, wmode, flagp);
    }
  }
}